// Round 5
// baseline (3778.123 us; speedup 1.0000x reference)
//
#include <hip/hip_runtime.h>

#define S 2048
#define NH 32
#define NEGF (-1e30f)

using bf16x8 = __attribute__((ext_vector_type(8))) __bf16;
using f32x4  = __attribute__((ext_vector_type(4))) float;
typedef unsigned int u32;
typedef unsigned short u16;
typedef unsigned long long u64;

__device__ __forceinline__ u16 f2bf(float f){
  u32 u = __float_as_uint(f);
  u32 r = (u + 0x7fffu + ((u >> 16) & 1u)) >> 16;
  return (u16)r;
}
__device__ __forceinline__ u32 fkey(float f){
  u32 u = __float_as_uint(f);
  return (u & 0x80000000u) ? ~u : (u | 0x80000000u);
}

// DPP 16-lane butterfly helpers (VALU pipe, no LDS traffic).
// lane = l4*16 + l15 -> reduce groups are exactly DPP rows of 16.
#define DPPF(ctrl, x) __int_as_float(__builtin_amdgcn_mov_dpp(__float_as_int(x), (ctrl), 0xf, 0xf, true))

// ---------------- f32 -> bf16 conversion (4 elems/thread) ----------------
__global__ __launch_bounds__(256) void cvt_bf16(const float* __restrict__ src,
                                                u32* __restrict__ dst, int n4) {
  int gid = blockIdx.x*256 + threadIdx.x;
  if (gid >= n4) return;
  float4 v = ((const float4*)src)[gid];
  uint2 o;
  o.x = (u32)f2bf(v.x) | ((u32)f2bf(v.y) << 16);
  o.y = (u32)f2bf(v.z) | ((u32)f2bf(v.w) << 16);
  ((uint2*)dst)[gid] = o;
}

// ---------------- concat idx_k_w (64x4096) + idx_gate_w (4x4096) -> [68,4096] ----------------
__global__ __launch_bounds__(256) void concat_ikg(const float* __restrict__ ikw,
                                                  const float* __restrict__ gw,
                                                  float* __restrict__ dst) {
  int gid = blockIdx.x*256 + threadIdx.x;   // 68*1024 float4
  if (gid >= 69632) return;
  float4 v = (gid < 65536) ? ((const float4*)ikw)[gid] : ((const float4*)gw)[gid - 65536];
  ((float4*)dst)[gid] = v;
}

// ---------------- fp32 GEMM v2: C[M,N] = A[M,K]*W[N,K]^T, 128x128 tile ----------------
__global__ __launch_bounds__(256) void gemm_f32_v2(const float* __restrict__ A,
                                                   const float* __restrict__ W,
                                                   float* __restrict__ C,
                                                   int M, int N, int K) {
  __shared__ float As[16][132];
  __shared__ float Bs[16][132];
  const int t = threadIdx.x;
  const int m0 = blockIdx.y << 7, n0 = blockIdx.x << 7;
  const int ty = t >> 4, tx = t & 15;
  const int sr = t >> 1, sc = (t & 1) << 3;   // staging: row 0..127, col-base 0/8
  const int nt = K >> 4;

  float pa[8], pb[8];
  auto prefetch = [&](int k0) {
    if (m0 + sr < M) {
      const float* ap = A + (size_t)(m0+sr)*K + k0 + sc;
      float4 u0 = *(const float4*)ap, u1 = *(const float4*)(ap+4);
      pa[0]=u0.x; pa[1]=u0.y; pa[2]=u0.z; pa[3]=u0.w;
      pa[4]=u1.x; pa[5]=u1.y; pa[6]=u1.z; pa[7]=u1.w;
    } else {
      #pragma unroll
      for (int j = 0; j < 8; ++j) pa[j] = 0.f;
    }
    if (n0 + sr < N) {
      const float* bp = W + (size_t)(n0+sr)*K + k0 + sc;
      float4 u0 = *(const float4*)bp, u1 = *(const float4*)(bp+4);
      pb[0]=u0.x; pb[1]=u0.y; pb[2]=u0.z; pb[3]=u0.w;
      pb[4]=u1.x; pb[5]=u1.y; pb[6]=u1.z; pb[7]=u1.w;
    } else {
      #pragma unroll
      for (int j = 0; j < 8; ++j) pb[j] = 0.f;
    }
  };
  auto stage_store = [&]() {
    #pragma unroll
    for (int j = 0; j < 8; ++j) {
      As[sc+j][sr] = pa[j];
      Bs[sc+j][sr] = pb[j];
    }
  };

  float acc[2][2][4][4] = {};

  prefetch(0);
  for (int kt = 0; kt < nt; ++kt) {
    __syncthreads();
    stage_store();
    if (kt + 1 < nt) prefetch((kt + 1) << 4);
    __builtin_amdgcn_sched_barrier(0);
    asm volatile("s_waitcnt lgkmcnt(0)" ::: "memory");
    __builtin_amdgcn_s_barrier();
    __builtin_amdgcn_sched_barrier(0);

    #pragma unroll
    for (int k = 0; k < 16; ++k) {
      float4 a0 = *(const float4*)(&As[k][ty*4]);
      float4 a1 = *(const float4*)(&As[k][64 + ty*4]);
      float4 b0 = *(const float4*)(&Bs[k][tx*4]);
      float4 b1 = *(const float4*)(&Bs[k][64 + tx*4]);
      float av[2][4] = {{a0.x,a0.y,a0.z,a0.w},{a1.x,a1.y,a1.z,a1.w}};
      float bv[2][4] = {{b0.x,b0.y,b0.z,b0.w},{b1.x,b1.y,b1.z,b1.w}};
      #pragma unroll
      for (int qa_ = 0; qa_ < 2; ++qa_)
        #pragma unroll
        for (int qb_ = 0; qb_ < 2; ++qb_)
          #pragma unroll
          for (int x = 0; x < 4; ++x)
            #pragma unroll
            for (int y = 0; y < 4; ++y)
              acc[qa_][qb_][x][y] += av[qa_][x]*bv[qb_][y];
    }
  }

  #pragma unroll
  for (int qa_ = 0; qa_ < 2; ++qa_)
    #pragma unroll
    for (int x = 0; x < 4; ++x) {
      int row = m0 + qa_*64 + ty*4 + x;
      if (row >= M) continue;
      #pragma unroll
      for (int qb_ = 0; qb_ < 2; ++qb_)
        #pragma unroll
        for (int y = 0; y < 4; ++y) {
          int col = n0 + qb_*64 + tx*4 + y;
          if (col < N) C[(size_t)row*N + col] = acc[qa_][qb_][x][y];
        }
    }
}

// ---------------- bf16 MFMA GEMM (guarded, for non-multiple shapes) ----------------
template<int OUTBF>
__global__ __launch_bounds__(256) void gemm_bf16k(const u16* __restrict__ A,
                                                  const u16* __restrict__ W,
                                                  void* __restrict__ C,
                                                  int M, int N, int K) {
  __shared__ __bf16 As[128][40];
  __shared__ __bf16 Bs[128][40];
  const int t = threadIdx.x;
  const int m0 = blockIdx.y << 7, n0 = blockIdx.x << 7;
  const int wave = t >> 6, lane = t & 63;
  const int wm = (wave >> 1) << 6, wn = (wave & 1) << 6;
  const int lr = lane & 15, ls = lane >> 4;
  f32x4 acc[4][4] = {};
  for (int k0 = 0; k0 < K; k0 += 32) {
    __syncthreads();
    #pragma unroll
    for (int s2 = 0; s2 < 2; ++s2) {
      int idx = t + (s2 << 8);
      int r = idx >> 2, c4 = (idx & 3) << 3;
      uint4 av = {0,0,0,0}, bv = {0,0,0,0};
      int gm = m0 + r, gn = n0 + r;
      if (gm < M) av = *(const uint4*)(A + (size_t)gm*K + k0 + c4);
      if (gn < N) bv = *(const uint4*)(W + (size_t)gn*K + k0 + c4);
      *(uint4*)(&As[r][c4]) = av;
      *(uint4*)(&Bs[r][c4]) = bv;
    }
    __syncthreads();
    bf16x8 af[4], bfr[4];
    #pragma unroll
    for (int x = 0; x < 4; ++x) af[x]  = *(const bf16x8*)(&As[wm + x*16 + lr][ls*8]);
    #pragma unroll
    for (int x = 0; x < 4; ++x) bfr[x] = *(const bf16x8*)(&Bs[wn + x*16 + lr][ls*8]);
    #pragma unroll
    for (int mi = 0; mi < 4; ++mi)
      #pragma unroll
      for (int ni = 0; ni < 4; ++ni)
        acc[mi][ni] = __builtin_amdgcn_mfma_f32_16x16x32_bf16(af[mi], bfr[ni], acc[mi][ni], 0, 0, 0);
  }
  #pragma unroll
  for (int mi = 0; mi < 4; ++mi)
    #pragma unroll
    for (int ni = 0; ni < 4; ++ni)
      #pragma unroll
      for (int r = 0; r < 4; ++r) {
        int row = m0 + wm + mi*16 + ls*4 + r;
        int col = n0 + wn + ni*16 + lr;
        if (row < M && col < N) {
          float v = acc[mi][ni][r];
          if (OUTBF) ((u16*)C)[(size_t)row*N + col] = f2bf(v);
          else       ((float*)C)[(size_t)row*N + col] = v;
        }
      }
}

// ---------------- bf16 MFMA GEMM with reg-prefetch pipeline ----------------
// M,N multiples of 128, K multiple of 32 (no guards). Same staging layout as
// gemm_bf16k but next k-tile's global loads are issued during the current
// tile's MFMAs and stay in flight across the raw s_barrier (proven pattern
// from gemm_f32_v2 / attn_pass1 — no global_load_lds).
template<int OUTBF>
__global__ __launch_bounds__(256) void gemm_bf16p(const u16* __restrict__ A,
                                                  const u16* __restrict__ W,
                                                  void* __restrict__ C,
                                                  int M, int N, int K) {
  __shared__ __bf16 As[128][40];
  __shared__ __bf16 Bs[128][40];
  const int t = threadIdx.x;
  const int m0 = blockIdx.y << 7, n0 = blockIdx.x << 7;
  const int wave = t >> 6, lane = t & 63;
  const int wm = (wave >> 1) << 6, wn = (wave & 1) << 6;
  const int lr = lane & 15, ls = lane >> 4;
  const int r0 = t >> 2, c0 = (t & 3) << 3;   // staging row / col-base (s2=0)
  const int nt = K >> 5;

  uint4 pa[2], pb[2];
  auto prefetch = [&](int k0) {
    #pragma unroll
    for (int s2 = 0; s2 < 2; ++s2) {
      int r = r0 + (s2 << 6);
      pa[s2] = *(const uint4*)(A + (size_t)(m0+r)*K + k0 + c0);
      pb[s2] = *(const uint4*)(W + (size_t)(n0+r)*K + k0 + c0);
    }
  };
  auto stage_store = [&]() {
    #pragma unroll
    for (int s2 = 0; s2 < 2; ++s2) {
      int r = r0 + (s2 << 6);
      *(uint4*)(&As[r][c0]) = pa[s2];
      *(uint4*)(&Bs[r][c0]) = pb[s2];
    }
  };

  f32x4 acc[4][4] = {};
  prefetch(0);
  for (int kt = 0; kt < nt; ++kt) {
    __syncthreads();                       // readers of prev tile done (+vmcnt of old loads)
    stage_store();                         // waits on this tile's loads (issued 1 iter ago)
    if (kt + 1 < nt) prefetch((kt + 1) << 5);
    __builtin_amdgcn_sched_barrier(0);
    asm volatile("s_waitcnt lgkmcnt(0)" ::: "memory");
    __builtin_amdgcn_s_barrier();
    __builtin_amdgcn_sched_barrier(0);

    bf16x8 af[4], bfr[4];
    #pragma unroll
    for (int x = 0; x < 4; ++x) af[x]  = *(const bf16x8*)(&As[wm + x*16 + lr][ls*8]);
    #pragma unroll
    for (int x = 0; x < 4; ++x) bfr[x] = *(const bf16x8*)(&Bs[wn + x*16 + lr][ls*8]);
    #pragma unroll
    for (int mi = 0; mi < 4; ++mi)
      #pragma unroll
      for (int ni = 0; ni < 4; ++ni)
        acc[mi][ni] = __builtin_amdgcn_mfma_f32_16x16x32_bf16(af[mi], bfr[ni], acc[mi][ni], 0, 0, 0);
  }
  #pragma unroll
  for (int mi = 0; mi < 4; ++mi)
    #pragma unroll
    for (int ni = 0; ni < 4; ++ni)
      #pragma unroll
      for (int r = 0; r < 4; ++r) {
        int row = m0 + wm + mi*16 + ls*4 + r;
        int col = n0 + wn + ni*16 + lr;
        float v = acc[mi][ni][r];
        if (OUTBF) ((u16*)C)[(size_t)row*N + col] = f2bf(v);
        else       ((float*)C)[(size_t)row*N + col] = v;
      }
}

// ---------------- RMSNorm (q path, 1536 cols, writes f32 in-place + bf16) ----------------
__global__ __launch_bounds__(256) void rms_q_kernel(float* __restrict__ qa,
                                                    const float* __restrict__ w,
                                                    u16* __restrict__ qres_b) {
  const int row = blockIdx.x, t = threadIdx.x;
  float* x = qa + (size_t)row*1536;
  float xs[6];
  float ss = 0.f;
  #pragma unroll
  for (int k = 0; k < 6; ++k) { xs[k] = x[t + k*256]; ss += xs[k]*xs[k]; }
  __shared__ float red[256];
  red[t] = ss; __syncthreads();
  for (int o = 128; o > 0; o >>= 1) { if (t < o) red[t] += red[t+o]; __syncthreads(); }
  float rms = rsqrtf(red[0]/1536.f + 1e-6f);
  #pragma unroll
  for (int k = 0; k < 6; ++k) {
    int c = t + k*256;
    float v = w[c] * (xs[k] * rms);
    x[c] = v;
    qres_b[(size_t)row*1536 + c] = f2bf(v);
  }
}

// ---------------- RMSNorm (kv path, first 512 of 576 cols -> bf16) ----------------
__global__ __launch_bounds__(256) void rms_kv_kernel(const float* __restrict__ ckv,
                                                     const float* __restrict__ w,
                                                     u16* __restrict__ kcomp) {
  const int row = blockIdx.x, t = threadIdx.x;
  const float* x = ckv + (size_t)row*576;
  float xs[2];
  float ss = 0.f;
  #pragma unroll
  for (int k = 0; k < 2; ++k) { xs[k] = x[t + k*256]; ss += xs[k]*xs[k]; }
  __shared__ float red[256];
  red[t] = ss; __syncthreads();
  for (int o = 128; o > 0; o >>= 1) { if (t < o) red[t] += red[t+o]; __syncthreads(); }
  float rms = rsqrtf(red[0]/512.f + 1e-6f);
  #pragma unroll
  for (int k = 0; k < 2; ++k) {
    int c = t + k*256;
    kcomp[(size_t)row*512 + c] = f2bf(w[c] * (xs[k] * rms));
  }
}

// ---------------- RoPE on q (in-place, bf16, dims 192..255) ----------------
__global__ __launch_bounds__(256) void rope_q_kernel(u16* __restrict__ q,
                                                     const float* __restrict__ cosb,
                                                     const float* __restrict__ sinb) {
  int gid = blockIdx.x*256 + threadIdx.x;      // 2048*32*32
  if (gid >= 2048*32*32) return;
  int i = gid >> 10, rem = gid & 1023;
  int h = rem >> 5, dd = rem & 31;
  size_t base = (size_t)i*8192 + h*256 + 192;
  float x1 = __uint_as_float(((u32)q[base+dd]) << 16);
  float x2 = __uint_as_float(((u32)q[base+dd+32]) << 16);
  float c1 = cosb[i*64+dd],   s1 = sinb[i*64+dd];
  float c2 = cosb[i*64+dd+32], s2 = sinb[i*64+dd+32];
  q[base+dd]    = f2bf(x1*c1 - x2*s1);
  q[base+dd+32] = f2bf(x2*c2 + x1*s2);
}

// ---------------- RoPE on k_pe (from ckv f32 cols 512..575 -> bf16 [2048,64]) ----------------
__global__ __launch_bounds__(256) void rope_k_kernel(const float* __restrict__ ckv,
                                                     const float* __restrict__ cosb,
                                                     const float* __restrict__ sinb,
                                                     u16* __restrict__ kpe) {
  int gid = blockIdx.x*256 + threadIdx.x;      // 2048*32
  if (gid >= 2048*32) return;
  int i = gid >> 5, dd = gid & 31;
  const float* xr = ckv + (size_t)i*576 + 512;
  float x1 = xr[dd], x2 = xr[dd+32];
  float c1 = cosb[i*64+dd],   s1 = sinb[i*64+dd];
  float c2 = cosb[i*64+dd+32], s2 = sinb[i*64+dd+32];
  kpe[(size_t)i*64+dd]    = f2bf(x1*c1 - x2*s1);
  kpe[(size_t)i*64+dd+32] = f2bf(x2*c2 + x1*s2);
}

// ---------------- transpose ikg [2048,68] -> ikT [64,2048] ----------------
__global__ __launch_bounds__(256) void transpose_ik(const float* __restrict__ ikg,
                                                    float* __restrict__ ikT) {
  int gid = blockIdx.x*256 + threadIdx.x;      // 64*2048
  if (gid >= 64*2048) return;
  int d = gid >> 11, j = gid & 2047;
  ikT[gid] = ikg[(size_t)j*68 + d];
}

// ---------------- indexer scores + exact top-512 (bitonic, jax tie-break) ----------------
__global__ __launch_bounds__(256) void topk_kernel(const float* __restrict__ iqv,
                                                   const float* __restrict__ ikT,
                                                   const float* __restrict__ ikg,
                                                   u32* __restrict__ maskbuf) {
  const int i = blockIdx.x, t = threadIdx.x;
  __shared__ float iqs[256];
  __shared__ float g[4];
  __shared__ u64 keys[2048];
  __shared__ u32 mk[64];
  iqs[t] = iqv[(size_t)i*256 + t];
  if (t < 4) g[t] = ikg[(size_t)i*68 + 64 + t];
  if (t < 64) mk[t] = 0;
  __syncthreads();
  float g0 = g[0], g1 = g[1], g2 = g[2], g3 = g[3];
  for (int j0 = 0; j0 < 2048; j0 += 256) {
    int j = j0 + t;
    float s;
    if (j > i) s = NEGF;
    else {
      float d0=0.f, d1=0.f, d2=0.f, d3=0.f;
      #pragma unroll 16
      for (int dd = 0; dd < 64; ++dd) {
        float v = ikT[dd*2048 + j];
        d0 += iqs[dd]*v; d1 += iqs[64+dd]*v; d2 += iqs[128+dd]*v; d3 += iqs[192+dd]*v;
      }
      s = g0*fmaxf(d0,0.f) + g1*fmaxf(d1,0.f) + g2*fmaxf(d2,0.f) + g3*fmaxf(d3,0.f);
    }
    keys[j] = ((u64)fkey(s) << 32) | (u32)(0xFFFFFFFFu - (u32)j);
  }
  __syncthreads();
  for (int k2 = 2; k2 <= 2048; k2 <<= 1) {
    for (int jj = k2 >> 1; jj > 0; jj >>= 1) {
      #pragma unroll 1
      for (int q8 = 0; q8 < 8; ++q8) {
        int x = t + (q8 << 8);
        int y = x ^ jj;
        if (y > x) {
          u64 kx = keys[x], ky = keys[y];
          if ((kx < ky) == ((x & k2) == 0)) { keys[x] = ky; keys[y] = kx; }
        }
      }
      __syncthreads();
    }
  }
  u32 ja = 0xFFFFFFFFu - (u32)(keys[t] & 0xFFFFFFFFull);
  u32 jb = 0xFFFFFFFFu - (u32)(keys[t+256] & 0xFFFFFFFFull);
  atomicOr(&mk[ja >> 5], 1u << (ja & 31));
  atomicOr(&mk[jb >> 5], 1u << (jb & 31));
  __syncthreads();
  if (t < 64) maskbuf[(size_t)i*64 + t] = mk[t];
}

// ---------------- MFMA flash attention pass1 ----------------
// DPP-based softmax butterfly (no LDS traffic for reduces); per-lane mask
// words loaded direct from global, prefetched one tile ahead.
__global__ __launch_bounds__(256, 3) void attn_pass1(
    const u16* __restrict__ qb, const u16* __restrict__ kvb,
    const u16* __restrict__ kpeb, const u32* __restrict__ maskbuf,
    float* __restrict__ probs, u16* __restrict__ attnb,
    float* __restrict__ Mb, float* __restrict__ Lb) {
  const int h = blockIdx.x & 31;
  const int qblk = 31 - (blockIdx.x >> 5);    // biggest-first
  const int i0 = qblk << 6;
  const int t = threadIdx.x;
  const int w = t >> 6;
  const int lane = t & 63;
  const int l15 = lane & 15, l4 = lane >> 4;
  const int i0w = i0 + (w << 4);

  __shared__ u16 Ks[32][264];       // keys x 256 dims, +8 pad (row 528B, 16-aligned)
  __shared__ u32 Vt2[16][260];      // key-pair x vdim (u32 = key-even | key-odd<<16), +4 pad
  __shared__ u16 Ps[4][16][40];     // per-wave P transform buffer

  const int c8 = t & 31;
  const int r0 = t >> 5;            // 0..7
  const u16* kbase = kvb + h*448;
  const u16* vbase = kvb + h*448 + 192;

  uint4 kreg[4];
  uint4 vreg0[2], vreg1[2];
  u32 mwn[4];

  auto prefetch = [&](int j0) {
    #pragma unroll
    for (int it = 0; it < 4; ++it) {
      int r = r0 + (it << 3);
      const u16* src = (c8 < 24)
        ? kbase + (size_t)(j0 + r)*14336 + c8*8
        : kpeb + (size_t)(j0 + r)*64 + (c8 - 24)*8;
      kreg[it] = *(const uint4*)src;
    }
    #pragma unroll
    for (int it = 0; it < 2; ++it) {
      int rp = r0 + (it << 3);
      const u16* vp = vbase + (size_t)(j0 + 2*rp)*14336 + c8*8;
      vreg0[it] = *(const uint4*)vp;
      vreg1[it] = *(const uint4*)(vp + 14336);
    }
  };
  auto prefetch_mask = [&](int jt) {
    #pragma unroll
    for (int r = 0; r < 4; ++r)
      mwn[r] = maskbuf[(size_t)(i0w + (l4<<2) + r)*64 + jt];
  };

  auto stage_store = [&]() {
    #pragma unroll
    for (int it = 0; it < 4; ++it)
      *(uint4*)(&Ks[r0 + (it << 3)][c8*8]) = kreg[it];
    #pragma unroll
    for (int it = 0; it < 2; ++it) {
      int rp = r0 + (it << 3);
      u32 a0 = vreg0[it].x, a1 = vreg0[it].y, a2 = vreg0[it].z, a3 = vreg0[it].w;
      u32 b0 = vreg1[it].x, b1 = vreg1[it].y, b2 = vreg1[it].z, b3 = vreg1[it].w;
      uint4 g0, g1;
      g0.x = (a0 & 0xffffu) | (b0 << 16);
      g0.y = (a0 >> 16)     | (b0 & 0xffff0000u);
      g0.z = (a1 & 0xffffu) | (b1 << 16);
      g0.w = (a1 >> 16)     | (b1 & 0xffff0000u);
      g1.x = (a2 & 0xffffu) | (b2 << 16);
      g1.y = (a2 >> 16)     | (b2 & 0xffff0000u);
      g1.z = (a3 & 0xffffu) | (b3 << 16);
      g1.w = (a3 >> 16)     | (b3 & 0xffff0000u);
      *(uint4*)(&Vt2[rp][c8*8])     = g0;
      *(uint4*)(&Vt2[rp][c8*8 + 4]) = g1;
    }
  };

  // Q fragments: A[m=l15][k=l4*8+e], 8 k-steps of 32
  bf16x8 qf[8];
  {
    const u16* qrow = qb + (size_t)(i0w + l15)*8192 + h*256 + l4*8;
    #pragma unroll
    for (int ks = 0; ks < 8; ++ks)
      qf[ks] = *(const bf16x8*)(qrow + ks*32);
  }
  f32x4 Of[16] = {};
  float mr[4] = {-INFINITY,-INFINITY,-INFINITY,-INFINITY};
  float lr[4] = {0.f,0.f,0.f,0.f};

  const int jt_end = (i0 + 63) >> 5;
  prefetch(0);
  prefetch_mask(0);
  for (int jt = 0; jt <= jt_end; ++jt) {
    const int j0 = jt << 5;
    __syncthreads();
    stage_store();                       // compiler inserts vmcnt waits for kreg/vreg
    u32 mword[4];
    #pragma unroll
    for (int r = 0; r < 4; ++r) mword[r] = mwn[r];
    if (jt < jt_end) { prefetch(j0 + 32); prefetch_mask(jt + 1); }
    __builtin_amdgcn_sched_barrier(0);
    asm volatile("s_waitcnt lgkmcnt(0)" ::: "memory");
    __builtin_amdgcn_s_barrier();
    __builtin_amdgcn_sched_barrier(0);   // rule #18: pin compute after the wait
    if (j0 > i0w + 15) continue;         // causal wave-level skip

    // S = Q K^T (2 key sub-tiles of 16)
    f32x4 sacc[2] = {};
    __builtin_amdgcn_s_setprio(1);
    #pragma unroll
    for (int nt = 0; nt < 2; ++nt)
      #pragma unroll
      for (int ks = 0; ks < 8; ++ks) {
        bf16x8 kf = *(const bf16x8*)(&Ks[nt*16 + l15][ks*32 + l4*8]);
        sacc[nt] = __builtin_amdgcn_mfma_f32_16x16x32_bf16(qf[ks], kf, sacc[nt], 0, 0, 0);
      }
    __builtin_amdgcn_s_setprio(0);

    float sv[2][4];
    #pragma unroll
    for (int nt = 0; nt < 2; ++nt)
      #pragma unroll
      for (int r = 0; r < 4; ++r) {
        int i_r = i0w + (l4<<2) + r;
        int j = j0 + nt*16 + l15;
        bool ok = (j <= i_r) && ((mword[r] >> (nt*16 + l15)) & 1u);
        sv[nt][r] = ok ? sacc[nt][r]*0.0625f : NEGF;
      }
    #pragma unroll
    for (int r = 0; r < 4; ++r) {
      int i_r = i0w + (l4<<2) + r;
      #pragma unroll
      for (int nt = 0; nt < 2; ++nt)
        if ((mword[r] >> (nt*16)) & 0xFFFFu)
          probs[((size_t)h*S + i_r)*S + j0 + nt*16 + l15] = sv[nt][r];
    }

    // online softmax: DPP butterfly over the 16-lane row group
    // {xor1, xor2, half_mirror(xor7), mirror(xor15)} spans the full group.
    float alpha[4];
    #pragma unroll
    for (int r = 0; r < 4; ++r) {
      float v = fmaxf(sv[0][r], sv[1][r]);
      v = fmaxf(v, DPPF(0xB1, v));    // quad_perm(1,0,3,2)
      v = fmaxf(v, DPPF(0x4E, v));    // quad_perm(2,3,0,1)
      v = fmaxf(v, DPPF(0x141, v));   // row_half_mirror
      v = fmaxf(v, DPPF(0x140, v));   // row_mirror
      float mn = fmaxf(mr[r], v);
      alpha[r] = (mn == mr[r]) ? 1.f : __expf(mr[r] - mn);
      mr[r] = mn;
    }
    float p0v[4], p1v[4];
    #pragma unroll
    for (int r = 0; r < 4; ++r) {
      float p0 = __expf(sv[0][r] - mr[r]);   // NEGF -> underflow 0
      float p1 = __expf(sv[1][r] - mr[r]);
      p0v[r] = p0; p1v[r] = p1;
      float rs = p0 + p1;
      rs += DPPF(0xB1, rs);
      rs += DPPF(0x4E, rs);
      rs += DPPF(0x141, rs);
      rs += DPPF(0x140, rs);
      lr[r] = lr[r]*alpha[r] + rs;
    }

    // P -> LDS (C-layout write), read back as A-frag
    #pragma unroll
    for (int r = 0; r < 4; ++r) {
      Ps[w][(l4<<2)+r][l15]      = f2bf(p0v[r]);
      Ps[w][(l4<<2)+r][16 + l15] = f2bf(p1v[r]);
    }
    bf16x8 pf = *(const bf16x8*)(&Ps[w][l15][l4*8]);

    // rescale O, then PV (V fragments from transposed Vt2, conflict-free b32 reads)
    #pragma unroll
    for (int vt = 0; vt < 16; ++vt)
      #pragma unroll
      for (int r = 0; r < 4; ++r)
        Of[vt][r] *= alpha[r];
    __builtin_amdgcn_s_setprio(1);
    #pragma unroll
    for (int vt = 0; vt < 16; ++vt) {
      uint4 uu;
      uu.x = Vt2[4*l4 + 0][vt*16 + l15];
      uu.y = Vt2[4*l4 + 1][vt*16 + l15];
      uu.z = Vt2[4*l4 + 2][vt*16 + l15];
      uu.w = Vt2[4*l4 + 3][vt*16 + l15];
      bf16x8 vf = *reinterpret_cast<const bf16x8*>(&uu);
      Of[vt] = __builtin_amdgcn_mfma_f32_16x16x32_bf16(pf, vf, Of[vt], 0, 0, 0);
    }
    __builtin_amdgcn_s_setprio(0);
  }

  // epilogue
  float invl[4];
  #pragma unroll
  for (int r = 0; r < 4; ++r) invl[r] = 1.f / lr[r];
  #pragma unroll
  for (int vt = 0; vt < 16; ++vt)
    #pragma unroll
    for (int r = 0; r < 4; ++r) {
      int i_r = i0w + (l4<<2) + r;
      attnb[(size_t)i_r*8192 + h*256 + vt*16 + l15] = f2bf(Of[vt][r]*invl[r]);
    }
  if (l15 == 0) {
    #pragma unroll
    for (int r = 0; r < 4; ++r) {
      Mb[(size_t)h*S + i0w + (l4<<2) + r] = mr[r];
      Lb[(size_t)h*S + i0w + (l4<<2) + r] = lr[r];
    }
  }
}

// ---------------- pass2: mask-aware softmax normalize of probs ----------------
__global__ __launch_bounds__(256) void attn_pass2(float* __restrict__ probs,
                                                  const float* __restrict__ Mb,
                                                  const float* __restrict__ Lb,
                                                  const u32* __restrict__ maskbuf) {
  const int i = blockIdx.x, h = blockIdx.y, t = threadIdx.x;
  const int j0 = t << 3;
  float* row = probs + ((size_t)h*S + i)*S;
  u32 bits = (maskbuf[(size_t)i*64 + (j0 >> 5)] >> (j0 & 31)) & 0xFFu;
  float4 o0 = {0.f,0.f,0.f,0.f}, o1 = {0.f,0.f,0.f,0.f};
  if (bits != 0 && j0 <= i) {
    const float m = Mb[(size_t)h*S + i];
    const float invl = 1.f / Lb[(size_t)h*S + i];
    float4 v0 = *(const float4*)(row + j0);
    float4 v1 = *(const float4*)(row + j0 + 4);
    o0.x = (((bits>>0)&1u) && j0+0 <= i) ? __expf(v0.x - m)*invl : 0.f;
    o0.y = (((bits>>1)&1u) && j0+1 <= i) ? __expf(v0.y - m)*invl : 0.f;
    o0.z = (((bits>>2)&1u) && j0+2 <= i) ? __expf(v0.z - m)*invl : 0.f;
    o0.w = (((bits>>3)&1u) && j0+3 <= i) ? __expf(v0.w - m)*invl : 0.f;
    o1.x = (((bits>>4)&1u) && j0+4 <= i) ? __expf(v1.x - m)*invl : 0.f;
    o1.y = (((bits>>5)&1u) && j0+5 <= i) ? __expf(v1.y - m)*invl : 0.f;
    o1.z = (((bits>>6)&1u) && j0+6 <= i) ? __expf(v1.z - m)*invl : 0.f;
    o1.w = (((bits>>7)&1u) && j0+7 <= i) ? __expf(v1.w - m)*invl : 0.f;
  }
  *(float4*)(row + j0) = o0;
  *(float4*)(row + j0 + 4) = o1;
}

// ---------------- host launch ----------------
extern "C" void kernel_launch(void* const* d_in, const int* in_sizes, int n_in,
                              void* d_out, int out_size, void* d_ws, size_t ws_size,
                              hipStream_t stream) {
  (void)in_sizes; (void)n_in; (void)out_size; (void)ws_size;
  const float* hidden    = (const float*)d_in[0];
  const float* cosb      = (const float*)d_in[1];
  const float* sinb      = (const float*)d_in[2];
  const float* q_a_w     = (const float*)d_in[3];
  const float* q_a_ln    = (const float*)d_in[4];
  const float* q_b_w     = (const float*)d_in[5];
  const float* kv_a_w    = (const float*)d_in[6];
  const float* kv_a_ln   = (const float*)d_in[7];
  const float* kv_b_w    = (const float*)d_in[8];
  const float* o_w       = (const float*)d_in[9];
  const float* idx_q_w   = (const float*)d_in[10];
  const float* idx_k_w   = (const float*)d_in[11];
  const float* idx_gate_w= (const float*)d_in[12];
  float* out   = (float*)d_out;
  float* probs = out + (size_t)2048*4096;

  char* wp = (char*)d_ws;
  auto alloc = [&](size_t bytes) { char* p = wp; wp += (bytes + 255) & ~(size_t)255; return p; };
  float* qa      = (float*)alloc((size_t)2048*1536*4);
  float* iq      = (float*)alloc((size_t)2048*256*4);
  float* ikg     = (float*)alloc((size_t)68*4096*4);
  float* ikgo    = (float*)alloc((size_t)2048*68*4);
  float* ikT     = (float*)alloc((size_t)64*2048*4);
  float* ckv     = (float*)alloc((size_t)2048*576*4);
  u16* hidden_b  = (u16*)alloc((size_t)2048*4096*2);
  u16* qres_b    = (u16*)alloc((size_t)2048*1536*2);
  u16* qbw_b     = (u16*)alloc((size_t)8192*1536*2);
  u16* kvaw_b    = (u16*)alloc((size_t)576*4096*2);
  u16* kvbw_b    = (u16*)alloc((size_t)14336*512*2);
  u16* ow_b      = (u16*)alloc((size_t)4096*8192*2);
  u16* qB        = (u16*)alloc((size_t)2048*8192*2);
  u16* kcomp_b   = (u16*)alloc((size_t)2048*512*2);
  u16* kpe_b     = (u16*)alloc((size_t)2048*64*2);
  u16* kvB       = (u16*)alloc((size_t)2048*14336*2);
  u16* attn_b    = (u16*)alloc((size_t)2048*8192*2);
  u32* maskb     = (u32*)alloc((size_t)2048*64*4);
  float* Mb      = (float*)alloc((size_t)32*2048*4);
  float* Lb      = (float*)alloc((size_t)32*2048*4);

  dim3 blk(256);
  // bf16 copies
  cvt_bf16<<<8192,  blk, 0, stream>>>(hidden, (u32*)hidden_b, 2097152);
  cvt_bf16<<<12288, blk, 0, stream>>>(q_b_w,  (u32*)qbw_b,   3145728);
  cvt_bf16<<<2304,  blk, 0, stream>>>(kv_a_w, (u32*)kvaw_b,   589824);
  cvt_bf16<<<7168,  blk, 0, stream>>>(kv_b_w, (u32*)kvbw_b,  1835008);
  cvt_bf16<<<32768, blk, 0, stream>>>(o_w,    (u32*)ow_b,    8388608);
  concat_ikg<<<272, blk, 0, stream>>>(idx_k_w, idx_gate_w, ikg);
  // fp32 precision path (indexer)
  gemm_f32_v2<<<dim3(12,16), blk, 0, stream>>>(hidden, q_a_w, qa,   2048, 1536, 4096);
  gemm_f32_v2<<<dim3(1,16),  blk, 0, stream>>>(hidden, ikg,   ikgo, 2048, 68,   4096);
  rms_q_kernel<<<2048, blk, 0, stream>>>(qa, q_a_ln, qres_b);
  gemm_f32_v2<<<dim3(2,16),  blk, 0, stream>>>(qa, idx_q_w, iq, 2048, 256, 1536);
  transpose_ik<<<512, blk, 0, stream>>>(ikgo, ikT);
  // bf16 path
  gemm_bf16k<0><<<dim3(5,16),   blk, 0, stream>>>(hidden_b, kvaw_b, ckv, 2048, 576,   4096);
  rms_kv_kernel<<<2048, blk, 0, stream>>>(ckv, kv_a_ln, kcomp_b);
  rope_k_kernel<<<256, blk, 0, stream>>>(ckv, cosb, sinb, kpe_b);
  gemm_bf16p<1><<<dim3(64,16),  blk, 0, stream>>>(qres_b, qbw_b, qB, 2048, 8192, 1536);
  rope_q_kernel<<<8192, blk, 0, stream>>>(qB, cosb, sinb);
  gemm_bf16p<1><<<dim3(112,16), blk, 0, stream>>>(kcomp_b, kvbw_b, kvB, 2048, 14336, 512);
  // top-k + attention
  topk_kernel<<<2048, blk, 0, stream>>>(iq, ikT, ikgo, maskb);
  attn_pass1<<<dim3(1024), blk, 0, stream>>>(qB, kvB, kpe_b, maskb, probs, attn_b, Mb, Lb);
  attn_pass2<<<dim3(2048,32), blk, 0, stream>>>(probs, Mb, Lb, maskb);
  // output projection
  gemm_bf16p<0><<<dim3(32,16), blk, 0, stream>>>(attn_b, ow_b, out, 2048, 4096, 8192);
}

// Round 6
// 3164.735 us; speedup vs baseline: 1.1938x; 1.1938x over previous
//
#include <hip/hip_runtime.h>

#define S 2048
#define NH 32
#define NEGF (-1e30f)

using bf16x8 = __attribute__((ext_vector_type(8))) __bf16;
using f32x4  = __attribute__((ext_vector_type(4))) float;
typedef unsigned int u32;
typedef unsigned short u16;
typedef unsigned long long u64;

__device__ __forceinline__ u16 f2bf(float f){
  u32 u = __float_as_uint(f);
  u32 r = (u + 0x7fffu + ((u >> 16) & 1u)) >> 16;
  return (u16)r;
}
__device__ __forceinline__ u32 fkey(float f){
  u32 u = __float_as_uint(f);
  return (u & 0x80000000u) ? ~u : (u | 0x80000000u);
}

// DPP 16-lane butterfly helpers (VALU pipe, no LDS traffic).
// lane = l4*16 + l15 -> reduce groups are exactly DPP rows of 16.
#define DPPF(ctrl, x) __int_as_float(__builtin_amdgcn_mov_dpp(__float_as_int(x), (ctrl), 0xf, 0xf, true))

// async global->LDS, 16 bytes per lane. HW writes to (wave-uniform base) +
// lane*16; callers MUST pass lane-linear lds pointers (verified below).
__device__ __forceinline__ void gload_lds16(const void* g, void* l){
  __builtin_amdgcn_global_load_lds((const __attribute__((address_space(1))) u32*)g,
                                   (__attribute__((address_space(3))) u32*)l, 16, 0, 0);
}

// ---------------- f32 -> bf16 conversion (4 elems/thread) ----------------
__global__ __launch_bounds__(256) void cvt_bf16(const float* __restrict__ src,
                                                u32* __restrict__ dst, int n4) {
  int gid = blockIdx.x*256 + threadIdx.x;
  if (gid >= n4) return;
  float4 v = ((const float4*)src)[gid];
  uint2 o;
  o.x = (u32)f2bf(v.x) | ((u32)f2bf(v.y) << 16);
  o.y = (u32)f2bf(v.z) | ((u32)f2bf(v.w) << 16);
  ((uint2*)dst)[gid] = o;
}

// ---------------- concat idx_k_w (64x4096) + idx_gate_w (4x4096) -> [68,4096] ----------------
__global__ __launch_bounds__(256) void concat_ikg(const float* __restrict__ ikw,
                                                  const float* __restrict__ gw,
                                                  float* __restrict__ dst) {
  int gid = blockIdx.x*256 + threadIdx.x;   // 68*1024 float4
  if (gid >= 69632) return;
  float4 v = (gid < 65536) ? ((const float4*)ikw)[gid] : ((const float4*)gw)[gid - 65536];
  ((float4*)dst)[gid] = v;
}

// ---------------- fp32 GEMM v2: C[M,N] = A[M,K]*W[N,K]^T, 128x128 tile ----------------
__global__ __launch_bounds__(256) void gemm_f32_v2(const float* __restrict__ A,
                                                   const float* __restrict__ W,
                                                   float* __restrict__ C,
                                                   int M, int N, int K) {
  __shared__ float As[16][132];
  __shared__ float Bs[16][132];
  const int t = threadIdx.x;
  const int m0 = blockIdx.y << 7, n0 = blockIdx.x << 7;
  const int ty = t >> 4, tx = t & 15;
  const int sr = t >> 1, sc = (t & 1) << 3;   // staging: row 0..127, col-base 0/8
  const int nt = K >> 4;

  float pa[8], pb[8];
  auto prefetch = [&](int k0) {
    if (m0 + sr < M) {
      const float* ap = A + (size_t)(m0+sr)*K + k0 + sc;
      float4 u0 = *(const float4*)ap, u1 = *(const float4*)(ap+4);
      pa[0]=u0.x; pa[1]=u0.y; pa[2]=u0.z; pa[3]=u0.w;
      pa[4]=u1.x; pa[5]=u1.y; pa[6]=u1.z; pa[7]=u1.w;
    } else {
      #pragma unroll
      for (int j = 0; j < 8; ++j) pa[j] = 0.f;
    }
    if (n0 + sr < N) {
      const float* bp = W + (size_t)(n0+sr)*K + k0 + sc;
      float4 u0 = *(const float4*)bp, u1 = *(const float4*)(bp+4);
      pb[0]=u0.x; pb[1]=u0.y; pb[2]=u0.z; pb[3]=u0.w;
      pb[4]=u1.x; pb[5]=u1.y; pb[6]=u1.z; pb[7]=u1.w;
    } else {
      #pragma unroll
      for (int j = 0; j < 8; ++j) pb[j] = 0.f;
    }
  };
  auto stage_store = [&]() {
    #pragma unroll
    for (int j = 0; j < 8; ++j) {
      As[sc+j][sr] = pa[j];
      Bs[sc+j][sr] = pb[j];
    }
  };

  float acc[2][2][4][4] = {};

  prefetch(0);
  for (int kt = 0; kt < nt; ++kt) {
    __syncthreads();
    stage_store();
    if (kt + 1 < nt) prefetch((kt + 1) << 4);
    __builtin_amdgcn_sched_barrier(0);
    asm volatile("s_waitcnt lgkmcnt(0)" ::: "memory");
    __builtin_amdgcn_s_barrier();
    __builtin_amdgcn_sched_barrier(0);

    #pragma unroll
    for (int k = 0; k < 16; ++k) {
      float4 a0 = *(const float4*)(&As[k][ty*4]);
      float4 a1 = *(const float4*)(&As[k][64 + ty*4]);
      float4 b0 = *(const float4*)(&Bs[k][tx*4]);
      float4 b1 = *(const float4*)(&Bs[k][64 + tx*4]);
      float av[2][4] = {{a0.x,a0.y,a0.z,a0.w},{a1.x,a1.y,a1.z,a1.w}};
      float bv[2][4] = {{b0.x,b0.y,b0.z,b0.w},{b1.x,b1.y,b1.z,b1.w}};
      #pragma unroll
      for (int qa_ = 0; qa_ < 2; ++qa_)
        #pragma unroll
        for (int qb_ = 0; qb_ < 2; ++qb_)
          #pragma unroll
          for (int x = 0; x < 4; ++x)
            #pragma unroll
            for (int y = 0; y < 4; ++y)
              acc[qa_][qb_][x][y] += av[qa_][x]*bv[qb_][y];
    }
  }

  #pragma unroll
  for (int qa_ = 0; qa_ < 2; ++qa_)
    #pragma unroll
    for (int x = 0; x < 4; ++x) {
      int row = m0 + qa_*64 + ty*4 + x;
      if (row >= M) continue;
      #pragma unroll
      for (int qb_ = 0; qb_ < 2; ++qb_)
        #pragma unroll
        for (int y = 0; y < 4; ++y) {
          int col = n0 + qb_*64 + tx*4 + y;
          if (col < N) C[(size_t)row*N + col] = acc[qa_][qb_][x][y];
        }
    }
}

// ---------------- bf16 MFMA GEMM (guarded, for non-multiple shapes) ----------------
template<int OUTBF>
__global__ __launch_bounds__(256) void gemm_bf16k(const u16* __restrict__ A,
                                                  const u16* __restrict__ W,
                                                  void* __restrict__ C,
                                                  int M, int N, int K) {
  __shared__ __bf16 As[128][40];
  __shared__ __bf16 Bs[128][40];
  const int t = threadIdx.x;
  const int m0 = blockIdx.y << 7, n0 = blockIdx.x << 7;
  const int wave = t >> 6, lane = t & 63;
  const int wm = (wave >> 1) << 6, wn = (wave & 1) << 6;
  const int lr = lane & 15, ls = lane >> 4;
  f32x4 acc[4][4] = {};
  for (int k0 = 0; k0 < K; k0 += 32) {
    __syncthreads();
    #pragma unroll
    for (int s2 = 0; s2 < 2; ++s2) {
      int idx = t + (s2 << 8);
      int r = idx >> 2, c4 = (idx & 3) << 3;
      uint4 av = {0,0,0,0}, bv = {0,0,0,0};
      int gm = m0 + r, gn = n0 + r;
      if (gm < M) av = *(const uint4*)(A + (size_t)gm*K + k0 + c4);
      if (gn < N) bv = *(const uint4*)(W + (size_t)gn*K + k0 + c4);
      *(uint4*)(&As[r][c4]) = av;
      *(uint4*)(&Bs[r][c4]) = bv;
    }
    __syncthreads();
    bf16x8 af[4], bfr[4];
    #pragma unroll
    for (int x = 0; x < 4; ++x) af[x]  = *(const bf16x8*)(&As[wm + x*16 + lr][ls*8]);
    #pragma unroll
    for (int x = 0; x < 4; ++x) bfr[x] = *(const bf16x8*)(&Bs[wn + x*16 + lr][ls*8]);
    #pragma unroll
    for (int mi = 0; mi < 4; ++mi)
      #pragma unroll
      for (int ni = 0; ni < 4; ++ni)
        acc[mi][ni] = __builtin_amdgcn_mfma_f32_16x16x32_bf16(af[mi], bfr[ni], acc[mi][ni], 0, 0, 0);
  }
  #pragma unroll
  for (int mi = 0; mi < 4; ++mi)
    #pragma unroll
    for (int ni = 0; ni < 4; ++ni)
      #pragma unroll
      for (int r = 0; r < 4; ++r) {
        int row = m0 + wm + mi*16 + ls*4 + r;
        int col = n0 + wn + ni*16 + lr;
        if (row < M && col < N) {
          float v = acc[mi][ni][r];
          if (OUTBF) ((u16*)C)[(size_t)row*N + col] = f2bf(v);
          else       ((float*)C)[(size_t)row*N + col] = v;
        }
      }
}

// ---------------- fast bf16 MFMA GEMM (m97 structure): M,N mult of 128, K mult of 32 ----------------
// global_load_lds width=16 into LINEAR no-pad LDS. Per wave the LDS dest is
// base + lane*16 exactly (idx = t + s2*256 is lane-linear; lane-0 ptr = wave
// base) — matches the HW wave-uniform-base contract. All writes in-bounds.
template<int OUTBF>
__global__ __launch_bounds__(256) void gemm_bf16f(const u16* __restrict__ A,
                                                  const u16* __restrict__ W,
                                                  void* __restrict__ C,
                                                  int M, int N, int K) {
  __shared__ u16 As[128*32];
  __shared__ u16 Bs[128*32];
  const int t = threadIdx.x;
  const int m0 = blockIdx.y << 7, n0 = blockIdx.x << 7;
  const int wave = t >> 6, lane = t & 63;
  const int wm = (wave >> 1) << 6, wn = (wave & 1) << 6;
  const int lr = lane & 15, ls = lane >> 4;
  f32x4 acc[4][4] = {};
  for (int k0 = 0; k0 < K; k0 += 32) {
    __syncthreads();                       // readers of prev tile done
    #pragma unroll
    for (int s2 = 0; s2 < 2; ++s2) {
      int idx = t + (s2 << 8);
      int r = idx >> 2, c8 = (idx & 3) << 3;
      gload_lds16(A + (size_t)(m0+r)*K + k0 + c8, As + idx*8);
      gload_lds16(W + (size_t)(n0+r)*K + k0 + c8, Bs + idx*8);
    }
    __syncthreads();                       // drains vmcnt(0): LDS data visible
    bf16x8 af[4], bfr[4];
    #pragma unroll
    for (int x = 0; x < 4; ++x) af[x]  = *(const bf16x8*)(As + (wm + x*16 + lr)*32 + ls*8);
    #pragma unroll
    for (int x = 0; x < 4; ++x) bfr[x] = *(const bf16x8*)(Bs + (wn + x*16 + lr)*32 + ls*8);
    #pragma unroll
    for (int mi = 0; mi < 4; ++mi)
      #pragma unroll
      for (int ni = 0; ni < 4; ++ni)
        acc[mi][ni] = __builtin_amdgcn_mfma_f32_16x16x32_bf16(af[mi], bfr[ni], acc[mi][ni], 0, 0, 0);
  }
  #pragma unroll
  for (int mi = 0; mi < 4; ++mi)
    #pragma unroll
    for (int ni = 0; ni < 4; ++ni)
      #pragma unroll
      for (int r = 0; r < 4; ++r) {
        int row = m0 + wm + mi*16 + ls*4 + r;
        int col = n0 + wn + ni*16 + lr;
        float v = acc[mi][ni][r];
        if (OUTBF) ((u16*)C)[(size_t)row*N + col] = f2bf(v);
        else       ((float*)C)[(size_t)row*N + col] = v;
      }
}

// ---------------- RMSNorm (q path, 1536 cols, writes f32 in-place + bf16) ----------------
__global__ __launch_bounds__(256) void rms_q_kernel(float* __restrict__ qa,
                                                    const float* __restrict__ w,
                                                    u16* __restrict__ qres_b) {
  const int row = blockIdx.x, t = threadIdx.x;
  float* x = qa + (size_t)row*1536;
  float xs[6];
  float ss = 0.f;
  #pragma unroll
  for (int k = 0; k < 6; ++k) { xs[k] = x[t + k*256]; ss += xs[k]*xs[k]; }
  __shared__ float red[256];
  red[t] = ss; __syncthreads();
  for (int o = 128; o > 0; o >>= 1) { if (t < o) red[t] += red[t+o]; __syncthreads(); }
  float rms = rsqrtf(red[0]/1536.f + 1e-6f);
  #pragma unroll
  for (int k = 0; k < 6; ++k) {
    int c = t + k*256;
    float v = w[c] * (xs[k] * rms);
    x[c] = v;
    qres_b[(size_t)row*1536 + c] = f2bf(v);
  }
}

// ---------------- RMSNorm (kv path, first 512 of 576 cols -> bf16) ----------------
__global__ __launch_bounds__(256) void rms_kv_kernel(const float* __restrict__ ckv,
                                                     const float* __restrict__ w,
                                                     u16* __restrict__ kcomp) {
  const int row = blockIdx.x, t = threadIdx.x;
  const float* x = ckv + (size_t)row*576;
  float xs[2];
  float ss = 0.f;
  #pragma unroll
  for (int k = 0; k < 2; ++k) { xs[k] = x[t + k*256]; ss += xs[k]*xs[k]; }
  __shared__ float red[256];
  red[t] = ss; __syncthreads();
  for (int o = 128; o > 0; o >>= 1) { if (t < o) red[t] += red[t+o]; __syncthreads(); }
  float rms = rsqrtf(red[0]/512.f + 1e-6f);
  #pragma unroll
  for (int k = 0; k < 2; ++k) {
    int c = t + k*256;
    kcomp[(size_t)row*512 + c] = f2bf(w[c] * (xs[k] * rms));
  }
}

// ---------------- RoPE on q (in-place, bf16, dims 192..255) ----------------
__global__ __launch_bounds__(256) void rope_q_kernel(u16* __restrict__ q,
                                                     const float* __restrict__ cosb,
                                                     const float* __restrict__ sinb) {
  int gid = blockIdx.x*256 + threadIdx.x;      // 2048*32*32
  if (gid >= 2048*32*32) return;
  int i = gid >> 10, rem = gid & 1023;
  int h = rem >> 5, dd = rem & 31;
  size_t base = (size_t)i*8192 + h*256 + 192;
  float x1 = __uint_as_float(((u32)q[base+dd]) << 16);
  float x2 = __uint_as_float(((u32)q[base+dd+32]) << 16);
  float c1 = cosb[i*64+dd],   s1 = sinb[i*64+dd];
  float c2 = cosb[i*64+dd+32], s2 = sinb[i*64+dd+32];
  q[base+dd]    = f2bf(x1*c1 - x2*s1);
  q[base+dd+32] = f2bf(x2*c2 + x1*s2);
}

// ---------------- RoPE on k_pe (from ckv f32 cols 512..575 -> bf16 [2048,64]) ----------------
__global__ __launch_bounds__(256) void rope_k_kernel(const float* __restrict__ ckv,
                                                     const float* __restrict__ cosb,
                                                     const float* __restrict__ sinb,
                                                     u16* __restrict__ kpe) {
  int gid = blockIdx.x*256 + threadIdx.x;      // 2048*32
  if (gid >= 2048*32) return;
  int i = gid >> 5, dd = gid & 31;
  const float* xr = ckv + (size_t)i*576 + 512;
  float x1 = xr[dd], x2 = xr[dd+32];
  float c1 = cosb[i*64+dd],   s1 = sinb[i*64+dd];
  float c2 = cosb[i*64+dd+32], s2 = sinb[i*64+dd+32];
  kpe[(size_t)i*64+dd]    = f2bf(x1*c1 - x2*s1);
  kpe[(size_t)i*64+dd+32] = f2bf(x2*c2 + x1*s2);
}

// ---------------- transpose ikg [2048,68] -> ikT [64,2048] ----------------
__global__ __launch_bounds__(256) void transpose_ik(const float* __restrict__ ikg,
                                                    float* __restrict__ ikT) {
  int gid = blockIdx.x*256 + threadIdx.x;      // 64*2048
  if (gid >= 64*2048) return;
  int d = gid >> 11, j = gid & 2047;
  ikT[gid] = ikg[(size_t)j*68 + d];
}

// ---------------- indexer scores + exact top-512 (bitonic, jax tie-break) ----------------
__global__ __launch_bounds__(256) void topk_kernel(const float* __restrict__ iqv,
                                                   const float* __restrict__ ikT,
                                                   const float* __restrict__ ikg,
                                                   u32* __restrict__ maskbuf) {
  const int i = blockIdx.x, t = threadIdx.x;
  __shared__ float iqs[256];
  __shared__ float g[4];
  __shared__ u64 keys[2048];
  __shared__ u32 mk[64];
  iqs[t] = iqv[(size_t)i*256 + t];
  if (t < 4) g[t] = ikg[(size_t)i*68 + 64 + t];
  if (t < 64) mk[t] = 0;
  __syncthreads();
  float g0 = g[0], g1 = g[1], g2 = g[2], g3 = g[3];
  for (int j0 = 0; j0 < 2048; j0 += 256) {
    int j = j0 + t;
    float s;
    if (j > i) s = NEGF;
    else {
      float d0=0.f, d1=0.f, d2=0.f, d3=0.f;
      #pragma unroll 16
      for (int dd = 0; dd < 64; ++dd) {
        float v = ikT[dd*2048 + j];
        d0 += iqs[dd]*v; d1 += iqs[64+dd]*v; d2 += iqs[128+dd]*v; d3 += iqs[192+dd]*v;
      }
      s = g0*fmaxf(d0,0.f) + g1*fmaxf(d1,0.f) + g2*fmaxf(d2,0.f) + g3*fmaxf(d3,0.f);
    }
    keys[j] = ((u64)fkey(s) << 32) | (u32)(0xFFFFFFFFu - (u32)j);
  }
  __syncthreads();
  for (int k2 = 2; k2 <= 2048; k2 <<= 1) {
    for (int jj = k2 >> 1; jj > 0; jj >>= 1) {
      #pragma unroll 1
      for (int q8 = 0; q8 < 8; ++q8) {
        int x = t + (q8 << 8);
        int y = x ^ jj;
        if (y > x) {
          u64 kx = keys[x], ky = keys[y];
          if ((kx < ky) == ((x & k2) == 0)) { keys[x] = ky; keys[y] = kx; }
        }
      }
      __syncthreads();
    }
  }
  u32 ja = 0xFFFFFFFFu - (u32)(keys[t] & 0xFFFFFFFFull);
  u32 jb = 0xFFFFFFFFu - (u32)(keys[t+256] & 0xFFFFFFFFull);
  atomicOr(&mk[ja >> 5], 1u << (ja & 31));
  atomicOr(&mk[jb >> 5], 1u << (jb & 31));
  __syncthreads();
  if (t < 64) maskbuf[(size_t)i*64 + t] = mk[t];
}

// ---------------- MFMA flash attention pass1 ----------------
// DPP-based softmax butterfly (no LDS traffic for reduces); per-lane mask
// words loaded direct from global, prefetched one tile ahead.
__global__ __launch_bounds__(256, 3) void attn_pass1(
    const u16* __restrict__ qb, const u16* __restrict__ kvb,
    const u16* __restrict__ kpeb, const u32* __restrict__ maskbuf,
    float* __restrict__ probs, u16* __restrict__ attnb,
    float* __restrict__ Mb, float* __restrict__ Lb) {
  const int h = blockIdx.x & 31;
  const int qblk = 31 - (blockIdx.x >> 5);    // biggest-first
  const int i0 = qblk << 6;
  const int t = threadIdx.x;
  const int w = t >> 6;
  const int lane = t & 63;
  const int l15 = lane & 15, l4 = lane >> 4;
  const int i0w = i0 + (w << 4);

  __shared__ u16 Ks[32][264];       // keys x 256 dims, +8 pad (row 528B, 16-aligned)
  __shared__ u32 Vt2[16][260];      // key-pair x vdim (u32 = key-even | key-odd<<16), +4 pad
  __shared__ u16 Ps[4][16][40];     // per-wave P transform buffer

  const int c8 = t & 31;
  const int r0 = t >> 5;            // 0..7
  const u16* kbase = kvb + h*448;
  const u16* vbase = kvb + h*448 + 192;

  uint4 kreg[4];
  uint4 vreg0[2], vreg1[2];
  u32 mwn[4];

  auto prefetch = [&](int j0) {
    #pragma unroll
    for (int it = 0; it < 4; ++it) {
      int r = r0 + (it << 3);
      const u16* src = (c8 < 24)
        ? kbase + (size_t)(j0 + r)*14336 + c8*8
        : kpeb + (size_t)(j0 + r)*64 + (c8 - 24)*8;
      kreg[it] = *(const uint4*)src;
    }
    #pragma unroll
    for (int it = 0; it < 2; ++it) {
      int rp = r0 + (it << 3);
      const u16* vp = vbase + (size_t)(j0 + 2*rp)*14336 + c8*8;
      vreg0[it] = *(const uint4*)vp;
      vreg1[it] = *(const uint4*)(vp + 14336);
    }
  };
  auto prefetch_mask = [&](int jt) {
    #pragma unroll
    for (int r = 0; r < 4; ++r)
      mwn[r] = maskbuf[(size_t)(i0w + (l4<<2) + r)*64 + jt];
  };

  auto stage_store = [&]() {
    #pragma unroll
    for (int it = 0; it < 4; ++it)
      *(uint4*)(&Ks[r0 + (it << 3)][c8*8]) = kreg[it];
    #pragma unroll
    for (int it = 0; it < 2; ++it) {
      int rp = r0 + (it << 3);
      u32 a0 = vreg0[it].x, a1 = vreg0[it].y, a2 = vreg0[it].z, a3 = vreg0[it].w;
      u32 b0 = vreg1[it].x, b1 = vreg1[it].y, b2 = vreg1[it].z, b3 = vreg1[it].w;
      uint4 g0, g1;
      g0.x = (a0 & 0xffffu) | (b0 << 16);
      g0.y = (a0 >> 16)     | (b0 & 0xffff0000u);
      g0.z = (a1 & 0xffffu) | (b1 << 16);
      g0.w = (a1 >> 16)     | (b1 & 0xffff0000u);
      g1.x = (a2 & 0xffffu) | (b2 << 16);
      g1.y = (a2 >> 16)     | (b2 & 0xffff0000u);
      g1.z = (a3 & 0xffffu) | (b3 << 16);
      g1.w = (a3 >> 16)     | (b3 & 0xffff0000u);
      *(uint4*)(&Vt2[rp][c8*8])     = g0;
      *(uint4*)(&Vt2[rp][c8*8 + 4]) = g1;
    }
  };

  // Q fragments: A[m=l15][k=l4*8+e], 8 k-steps of 32
  bf16x8 qf[8];
  {
    const u16* qrow = qb + (size_t)(i0w + l15)*8192 + h*256 + l4*8;
    #pragma unroll
    for (int ks = 0; ks < 8; ++ks)
      qf[ks] = *(const bf16x8*)(qrow + ks*32);
  }
  f32x4 Of[16] = {};
  float mr[4] = {-INFINITY,-INFINITY,-INFINITY,-INFINITY};
  float lr[4] = {0.f,0.f,0.f,0.f};

  const int jt_end = (i0 + 63) >> 5;
  prefetch(0);
  prefetch_mask(0);
  for (int jt = 0; jt <= jt_end; ++jt) {
    const int j0 = jt << 5;
    __syncthreads();
    stage_store();                       // compiler inserts vmcnt waits for kreg/vreg
    u32 mword[4];
    #pragma unroll
    for (int r = 0; r < 4; ++r) mword[r] = mwn[r];
    if (jt < jt_end) { prefetch(j0 + 32); prefetch_mask(jt + 1); }
    __builtin_amdgcn_sched_barrier(0);
    asm volatile("s_waitcnt lgkmcnt(0)" ::: "memory");
    __builtin_amdgcn_s_barrier();
    __builtin_amdgcn_sched_barrier(0);   // rule #18: pin compute after the wait
    if (j0 > i0w + 15) continue;         // causal wave-level skip

    // S = Q K^T (2 key sub-tiles of 16)
    f32x4 sacc[2] = {};
    __builtin_amdgcn_s_setprio(1);
    #pragma unroll
    for (int nt = 0; nt < 2; ++nt)
      #pragma unroll
      for (int ks = 0; ks < 8; ++ks) {
        bf16x8 kf = *(const bf16x8*)(&Ks[nt*16 + l15][ks*32 + l4*8]);
        sacc[nt] = __builtin_amdgcn_mfma_f32_16x16x32_bf16(qf[ks], kf, sacc[nt], 0, 0, 0);
      }
    __builtin_amdgcn_s_setprio(0);

    float sv[2][4];
    #pragma unroll
    for (int nt = 0; nt < 2; ++nt)
      #pragma unroll
      for (int r = 0; r < 4; ++r) {
        int i_r = i0w + (l4<<2) + r;
        int j = j0 + nt*16 + l15;
        bool ok = (j <= i_r) && ((mword[r] >> (nt*16 + l15)) & 1u);
        sv[nt][r] = ok ? sacc[nt][r]*0.0625f : NEGF;
      }
    #pragma unroll
    for (int r = 0; r < 4; ++r) {
      int i_r = i0w + (l4<<2) + r;
      #pragma unroll
      for (int nt = 0; nt < 2; ++nt)
        if ((mword[r] >> (nt*16)) & 0xFFFFu)
          probs[((size_t)h*S + i_r)*S + j0 + nt*16 + l15] = sv[nt][r];
    }

    // online softmax: DPP butterfly over the 16-lane row group
    // {xor1, xor2, half_mirror(xor7), mirror(xor15)} spans the full group.
    float alpha[4];
    #pragma unroll
    for (int r = 0; r < 4; ++r) {
      float v = fmaxf(sv[0][r], sv[1][r]);
      v = fmaxf(v, DPPF(0xB1, v));    // quad_perm(1,0,3,2)
      v = fmaxf(v, DPPF(0x4E, v));    // quad_perm(2,3,0,1)
      v = fmaxf(v, DPPF(0x141, v));   // row_half_mirror
      v = fmaxf(v, DPPF(0x140, v));   // row_mirror
      float mn = fmaxf(mr[r], v);
      alpha[r] = (mn == mr[r]) ? 1.f : __expf(mr[r] - mn);
      mr[r] = mn;
    }
    float p0v[4], p1v[4];
    #pragma unroll
    for (int r = 0; r < 4; ++r) {
      float p0 = __expf(sv[0][r] - mr[r]);   // NEGF -> underflow 0
      float p1 = __expf(sv[1][r] - mr[r]);
      p0v[r] = p0; p1v[r] = p1;
      float rs = p0 + p1;
      rs += DPPF(0xB1, rs);
      rs += DPPF(0x4E, rs);
      rs += DPPF(0x141, rs);
      rs += DPPF(0x140, rs);
      lr[r] = lr[r]*alpha[r] + rs;
    }

    // P -> LDS (C-layout write), read back as A-frag
    #pragma unroll
    for (int r = 0; r < 4; ++r) {
      Ps[w][(l4<<2)+r][l15]      = f2bf(p0v[r]);
      Ps[w][(l4<<2)+r][16 + l15] = f2bf(p1v[r]);
    }
    bf16x8 pf = *(const bf16x8*)(&Ps[w][l15][l4*8]);

    // rescale O, then PV (V fragments from transposed Vt2, conflict-free b32 reads)
    #pragma unroll
    for (int vt = 0; vt < 16; ++vt)
      #pragma unroll
      for (int r = 0; r < 4; ++r)
        Of[vt][r] *= alpha[r];
    __builtin_amdgcn_s_setprio(1);
    #pragma unroll
    for (int vt = 0; vt < 16; ++vt) {
      uint4 uu;
      uu.x = Vt2[4*l4 + 0][vt*16 + l15];
      uu.y = Vt2[4*l4 + 1][vt*16 + l15];
      uu.z = Vt2[4*l4 + 2][vt*16 + l15];
      uu.w = Vt2[4*l4 + 3][vt*16 + l15];
      bf16x8 vf = *reinterpret_cast<const bf16x8*>(&uu);
      Of[vt] = __builtin_amdgcn_mfma_f32_16x16x32_bf16(pf, vf, Of[vt], 0, 0, 0);
    }
    __builtin_amdgcn_s_setprio(0);
  }

  // epilogue
  float invl[4];
  #pragma unroll
  for (int r = 0; r < 4; ++r) invl[r] = 1.f / lr[r];
  #pragma unroll
  for (int vt = 0; vt < 16; ++vt)
    #pragma unroll
    for (int r = 0; r < 4; ++r) {
      int i_r = i0w + (l4<<2) + r;
      attnb[(size_t)i_r*8192 + h*256 + vt*16 + l15] = f2bf(Of[vt][r]*invl[r]);
    }
  if (l15 == 0) {
    #pragma unroll
    for (int r = 0; r < 4; ++r) {
      Mb[(size_t)h*S + i0w + (l4<<2) + r] = mr[r];
      Lb[(size_t)h*S + i0w + (l4<<2) + r] = lr[r];
    }
  }
}

// ---------------- pass2: mask-aware softmax normalize of probs ----------------
__global__ __launch_bounds__(256) void attn_pass2(float* __restrict__ probs,
                                                  const float* __restrict__ Mb,
                                                  const float* __restrict__ Lb,
                                                  const u32* __restrict__ maskbuf) {
  const int i = blockIdx.x, h = blockIdx.y, t = threadIdx.x;
  const int j0 = t << 3;
  float* row = probs + ((size_t)h*S + i)*S;
  u32 bits = (maskbuf[(size_t)i*64 + (j0 >> 5)] >> (j0 & 31)) & 0xFFu;
  float4 o0 = {0.f,0.f,0.f,0.f}, o1 = {0.f,0.f,0.f,0.f};
  if (bits != 0 && j0 <= i) {
    const float m = Mb[(size_t)h*S + i];
    const float invl = 1.f / Lb[(size_t)h*S + i];
    float4 v0 = *(const float4*)(row + j0);
    float4 v1 = *(const float4*)(row + j0 + 4);
    o0.x = (((bits>>0)&1u) && j0+0 <= i) ? __expf(v0.x - m)*invl : 0.f;
    o0.y = (((bits>>1)&1u) && j0+1 <= i) ? __expf(v0.y - m)*invl : 0.f;
    o0.z = (((bits>>2)&1u) && j0+2 <= i) ? __expf(v0.z - m)*invl : 0.f;
    o0.w = (((bits>>3)&1u) && j0+3 <= i) ? __expf(v0.w - m)*invl : 0.f;
    o1.x = (((bits>>4)&1u) && j0+4 <= i) ? __expf(v1.x - m)*invl : 0.f;
    o1.y = (((bits>>5)&1u) && j0+5 <= i) ? __expf(v1.y - m)*invl : 0.f;
    o1.z = (((bits>>6)&1u) && j0+6 <= i) ? __expf(v1.z - m)*invl : 0.f;
    o1.w = (((bits>>7)&1u) && j0+7 <= i) ? __expf(v1.w - m)*invl : 0.f;
  }
  *(float4*)(row + j0) = o0;
  *(float4*)(row + j0 + 4) = o1;
}

// ---------------- host launch ----------------
extern "C" void kernel_launch(void* const* d_in, const int* in_sizes, int n_in,
                              void* d_out, int out_size, void* d_ws, size_t ws_size,
                              hipStream_t stream) {
  (void)in_sizes; (void)n_in; (void)out_size; (void)ws_size;
  const float* hidden    = (const float*)d_in[0];
  const float* cosb      = (const float*)d_in[1];
  const float* sinb      = (const float*)d_in[2];
  const float* q_a_w     = (const float*)d_in[3];
  const float* q_a_ln    = (const float*)d_in[4];
  const float* q_b_w     = (const float*)d_in[5];
  const float* kv_a_w    = (const float*)d_in[6];
  const float* kv_a_ln   = (const float*)d_in[7];
  const float* kv_b_w    = (const float*)d_in[8];
  const float* o_w       = (const float*)d_in[9];
  const float* idx_q_w   = (const float*)d_in[10];
  const float* idx_k_w   = (const float*)d_in[11];
  const float* idx_gate_w= (const float*)d_in[12];
  float* out   = (float*)d_out;
  float* probs = out + (size_t)2048*4096;

  char* wp = (char*)d_ws;
  auto alloc = [&](size_t bytes) { char* p = wp; wp += (bytes + 255) & ~(size_t)255; return p; };
  float* qa      = (float*)alloc((size_t)2048*1536*4);
  float* iq      = (float*)alloc((size_t)2048*256*4);
  float* ikg     = (float*)alloc((size_t)68*4096*4);
  float* ikgo    = (float*)alloc((size_t)2048*68*4);
  float* ikT     = (float*)alloc((size_t)64*2048*4);
  float* ckv     = (float*)alloc((size_t)2048*576*4);
  u16* hidden_b  = (u16*)alloc((size_t)2048*4096*2);
  u16* qres_b    = (u16*)alloc((size_t)2048*1536*2);
  u16* qbw_b     = (u16*)alloc((size_t)8192*1536*2);
  u16* kvaw_b    = (u16*)alloc((size_t)576*4096*2);
  u16* kvbw_b    = (u16*)alloc((size_t)14336*512*2);
  u16* ow_b      = (u16*)alloc((size_t)4096*8192*2);
  u16* qB        = (u16*)alloc((size_t)2048*8192*2);
  u16* kcomp_b   = (u16*)alloc((size_t)2048*512*2);
  u16* kpe_b     = (u16*)alloc((size_t)2048*64*2);
  u16* kvB       = (u16*)alloc((size_t)2048*14336*2);
  u16* attn_b    = (u16*)alloc((size_t)2048*8192*2);
  u32* maskb     = (u32*)alloc((size_t)2048*64*4);
  float* Mb      = (float*)alloc((size_t)32*2048*4);
  float* Lb      = (float*)alloc((size_t)32*2048*4);

  dim3 blk(256);
  // bf16 copies
  cvt_bf16<<<8192,  blk, 0, stream>>>(hidden, (u32*)hidden_b, 2097152);
  cvt_bf16<<<12288, blk, 0, stream>>>(q_b_w,  (u32*)qbw_b,   3145728);
  cvt_bf16<<<2304,  blk, 0, stream>>>(kv_a_w, (u32*)kvaw_b,   589824);
  cvt_bf16<<<7168,  blk, 0, stream>>>(kv_b_w, (u32*)kvbw_b,  1835008);
  cvt_bf16<<<32768, blk, 0, stream>>>(o_w,    (u32*)ow_b,    8388608);
  concat_ikg<<<272, blk, 0, stream>>>(idx_k_w, idx_gate_w, ikg);
  // fp32 precision path (indexer)
  gemm_f32_v2<<<dim3(12,16), blk, 0, stream>>>(hidden, q_a_w, qa,   2048, 1536, 4096);
  gemm_f32_v2<<<dim3(1,16),  blk, 0, stream>>>(hidden, ikg,   ikgo, 2048, 68,   4096);
  rms_q_kernel<<<2048, blk, 0, stream>>>(qa, q_a_ln, qres_b);
  gemm_f32_v2<<<dim3(2,16),  blk, 0, stream>>>(qa, idx_q_w, iq, 2048, 256, 1536);
  transpose_ik<<<512, blk, 0, stream>>>(ikgo, ikT);
  // bf16 path
  gemm_bf16k<0><<<dim3(5,16),   blk, 0, stream>>>(hidden_b, kvaw_b, ckv, 2048, 576,   4096);
  rms_kv_kernel<<<2048, blk, 0, stream>>>(ckv, kv_a_ln, kcomp_b);
  rope_k_kernel<<<256, blk, 0, stream>>>(ckv, cosb, sinb, kpe_b);
  gemm_bf16f<1><<<dim3(64,16),  blk, 0, stream>>>(qres_b, qbw_b, qB, 2048, 8192, 1536);
  rope_q_kernel<<<8192, blk, 0, stream>>>(qB, cosb, sinb);
  gemm_bf16f<1><<<dim3(112,16), blk, 0, stream>>>(kcomp_b, kvbw_b, kvB, 2048, 14336, 512);
  // top-k + attention
  topk_kernel<<<2048, blk, 0, stream>>>(iq, ikT, ikgo, maskb);
  attn_pass1<<<dim3(1024), blk, 0, stream>>>(qB, kvB, kpe_b, maskb, probs, attn_b, Mb, Lb);
  attn_pass2<<<dim3(2048,32), blk, 0, stream>>>(probs, Mb, Lb, maskb);
  // output projection
  gemm_bf16f<0><<<dim3(32,16), blk, 0, stream>>>(attn_b, ow_b, out, 2048, 4096, 8192);
}

// Round 7
// 2517.823 us; speedup vs baseline: 1.5006x; 1.2569x over previous
//
#include <hip/hip_runtime.h>

#define S 2048
#define NH 32
#define NEGF (-1e30f)

using bf16x8 = __attribute__((ext_vector_type(8))) __bf16;
using f32x4  = __attribute__((ext_vector_type(4))) float;
typedef unsigned int u32;
typedef unsigned short u16;
typedef unsigned long long u64;

__device__ __forceinline__ u16 f2bf(float f){
  u32 u = __float_as_uint(f);
  u32 r = (u + 0x7fffu + ((u >> 16) & 1u)) >> 16;
  return (u16)r;
}
__device__ __forceinline__ u32 fkey(float f){
  u32 u = __float_as_uint(f);
  return (u & 0x80000000u) ? ~u : (u | 0x80000000u);
}

// DPP 16-lane butterfly helpers (VALU pipe, no LDS traffic).
// lane = l4*16 + l15 -> reduce groups are exactly DPP rows of 16.
#define DPPF(ctrl, x) __int_as_float(__builtin_amdgcn_mov_dpp(__float_as_int(x), (ctrl), 0xf, 0xf, true))

// async global->LDS, 16 bytes per lane. HW writes to (wave-uniform base) +
// lane*16; callers MUST pass lane-linear lds pointers.
__device__ __forceinline__ void gload_lds16(const void* g, void* l){
  __builtin_amdgcn_global_load_lds((const __attribute__((address_space(1))) u32*)g,
                                   (__attribute__((address_space(3))) u32*)l, 16, 0, 0);
}

// ---------------- f32 -> bf16 conversion (4 elems/thread) ----------------
__global__ __launch_bounds__(256) void cvt_bf16(const float* __restrict__ src,
                                                u32* __restrict__ dst, int n4) {
  int gid = blockIdx.x*256 + threadIdx.x;
  if (gid >= n4) return;
  float4 v = ((const float4*)src)[gid];
  uint2 o;
  o.x = (u32)f2bf(v.x) | ((u32)f2bf(v.y) << 16);
  o.y = (u32)f2bf(v.z) | ((u32)f2bf(v.w) << 16);
  ((uint2*)dst)[gid] = o;
}

// ---------------- concat idx_k_w (64x4096) + idx_gate_w (4x4096) -> [68,4096] ----------------
__global__ __launch_bounds__(256) void concat_ikg(const float* __restrict__ ikw,
                                                  const float* __restrict__ gw,
                                                  float* __restrict__ dst) {
  int gid = blockIdx.x*256 + threadIdx.x;   // 68*1024 float4
  if (gid >= 69632) return;
  float4 v = (gid < 65536) ? ((const float4*)ikw)[gid] : ((const float4*)gw)[gid - 65536];
  ((float4*)dst)[gid] = v;
}

// ---------------- fp32 GEMM v3: split-K partials. 128x128 tile ----------------
// blockIdx.z picks K-chunk [z*kchunk, (z+1)*kchunk); writes C_part + z*M*N.
__global__ __launch_bounds__(256) void gemm_f32_v3(const float* __restrict__ A,
                                                   const float* __restrict__ W,
                                                   float* __restrict__ C_part,
                                                   int M, int N, int K, int kchunk) {
  __shared__ float As[16][132];
  __shared__ float Bs[16][132];
  const int t = threadIdx.x;
  const int m0 = blockIdx.y << 7, n0 = blockIdx.x << 7;
  const int kz = blockIdx.z;
  const int kbeg = kz * kchunk;
  const int nt = kchunk >> 4;
  const int ty = t >> 4, tx = t & 15;
  const int sr = t >> 1, sc = (t & 1) << 3;   // staging: row 0..127, col-base 0/8
  float* C = C_part + (size_t)kz * M * N;

  float pa[8], pb[8];
  auto prefetch = [&](int k0) {
    if (m0 + sr < M) {
      const float* ap = A + (size_t)(m0+sr)*K + k0 + sc;
      float4 u0 = *(const float4*)ap, u1 = *(const float4*)(ap+4);
      pa[0]=u0.x; pa[1]=u0.y; pa[2]=u0.z; pa[3]=u0.w;
      pa[4]=u1.x; pa[5]=u1.y; pa[6]=u1.z; pa[7]=u1.w;
    } else {
      #pragma unroll
      for (int j = 0; j < 8; ++j) pa[j] = 0.f;
    }
    if (n0 + sr < N) {
      const float* bp = W + (size_t)(n0+sr)*K + k0 + sc;
      float4 u0 = *(const float4*)bp, u1 = *(const float4*)(bp+4);
      pb[0]=u0.x; pb[1]=u0.y; pb[2]=u0.z; pb[3]=u0.w;
      pb[4]=u1.x; pb[5]=u1.y; pb[6]=u1.z; pb[7]=u1.w;
    } else {
      #pragma unroll
      for (int j = 0; j < 8; ++j) pb[j] = 0.f;
    }
  };
  auto stage_store = [&]() {
    #pragma unroll
    for (int j = 0; j < 8; ++j) {
      As[sc+j][sr] = pa[j];
      Bs[sc+j][sr] = pb[j];
    }
  };

  float acc[2][2][4][4] = {};

  prefetch(kbeg);
  for (int kt = 0; kt < nt; ++kt) {
    __syncthreads();
    stage_store();
    if (kt + 1 < nt) prefetch(kbeg + ((kt + 1) << 4));
    __builtin_amdgcn_sched_barrier(0);
    asm volatile("s_waitcnt lgkmcnt(0)" ::: "memory");
    __builtin_amdgcn_s_barrier();
    __builtin_amdgcn_sched_barrier(0);

    #pragma unroll
    for (int k = 0; k < 16; ++k) {
      float4 a0 = *(const float4*)(&As[k][ty*4]);
      float4 a1 = *(const float4*)(&As[k][64 + ty*4]);
      float4 b0 = *(const float4*)(&Bs[k][tx*4]);
      float4 b1 = *(const float4*)(&Bs[k][64 + tx*4]);
      float av[2][4] = {{a0.x,a0.y,a0.z,a0.w},{a1.x,a1.y,a1.z,a1.w}};
      float bv[2][4] = {{b0.x,b0.y,b0.z,b0.w},{b1.x,b1.y,b1.z,b1.w}};
      #pragma unroll
      for (int qa_ = 0; qa_ < 2; ++qa_)
        #pragma unroll
        for (int qb_ = 0; qb_ < 2; ++qb_)
          #pragma unroll
          for (int x = 0; x < 4; ++x)
            #pragma unroll
            for (int y = 0; y < 4; ++y)
              acc[qa_][qb_][x][y] += av[qa_][x]*bv[qb_][y];
    }
  }

  #pragma unroll
  for (int qa_ = 0; qa_ < 2; ++qa_)
    #pragma unroll
    for (int x = 0; x < 4; ++x) {
      int row = m0 + qa_*64 + ty*4 + x;
      if (row >= M) continue;
      #pragma unroll
      for (int qb_ = 0; qb_ < 2; ++qb_)
        #pragma unroll
        for (int y = 0; y < 4; ++y) {
          int col = n0 + qb_*64 + tx*4 + y;
          if (col < N) C[(size_t)row*N + col] = acc[qa_][qb_][x][y];
        }
    }
}

// sum `splits` partial C planes (float4-vectorized, fixed order)
__global__ __launch_bounds__(256) void reduce_part(const float* __restrict__ part,
                                                   float* __restrict__ C,
                                                   int n4, int splits) {
  int gid = blockIdx.x*256 + threadIdx.x;
  if (gid >= n4) return;
  float4 a = ((const float4*)part)[gid];
  for (int s = 1; s < splits; ++s) {
    float4 b = ((const float4*)part)[(size_t)s*n4 + gid];
    a.x += b.x; a.y += b.y; a.z += b.z; a.w += b.w;
  }
  ((float4*)C)[gid] = a;
}

// ---------------- fp32 GEMM v2 (fallback, single-launch): 128x128 tile ----------------
__global__ __launch_bounds__(256) void gemm_f32_v2(const float* __restrict__ A,
                                                   const float* __restrict__ W,
                                                   float* __restrict__ C,
                                                   int M, int N, int K) {
  __shared__ float As[16][132];
  __shared__ float Bs[16][132];
  const int t = threadIdx.x;
  const int m0 = blockIdx.y << 7, n0 = blockIdx.x << 7;
  const int ty = t >> 4, tx = t & 15;
  const int sr = t >> 1, sc = (t & 1) << 3;
  const int nt = K >> 4;

  float pa[8], pb[8];
  auto prefetch = [&](int k0) {
    if (m0 + sr < M) {
      const float* ap = A + (size_t)(m0+sr)*K + k0 + sc;
      float4 u0 = *(const float4*)ap, u1 = *(const float4*)(ap+4);
      pa[0]=u0.x; pa[1]=u0.y; pa[2]=u0.z; pa[3]=u0.w;
      pa[4]=u1.x; pa[5]=u1.y; pa[6]=u1.z; pa[7]=u1.w;
    } else {
      #pragma unroll
      for (int j = 0; j < 8; ++j) pa[j] = 0.f;
    }
    if (n0 + sr < N) {
      const float* bp = W + (size_t)(n0+sr)*K + k0 + sc;
      float4 u0 = *(const float4*)bp, u1 = *(const float4*)(bp+4);
      pb[0]=u0.x; pb[1]=u0.y; pb[2]=u0.z; pb[3]=u0.w;
      pb[4]=u1.x; pb[5]=u1.y; pb[6]=u1.z; pb[7]=u1.w;
    } else {
      #pragma unroll
      for (int j = 0; j < 8; ++j) pb[j] = 0.f;
    }
  };
  auto stage_store = [&]() {
    #pragma unroll
    for (int j = 0; j < 8; ++j) {
      As[sc+j][sr] = pa[j];
      Bs[sc+j][sr] = pb[j];
    }
  };

  float acc[2][2][4][4] = {};

  prefetch(0);
  for (int kt = 0; kt < nt; ++kt) {
    __syncthreads();
    stage_store();
    if (kt + 1 < nt) prefetch((kt + 1) << 4);
    __builtin_amdgcn_sched_barrier(0);
    asm volatile("s_waitcnt lgkmcnt(0)" ::: "memory");
    __builtin_amdgcn_s_barrier();
    __builtin_amdgcn_sched_barrier(0);

    #pragma unroll
    for (int k = 0; k < 16; ++k) {
      float4 a0 = *(const float4*)(&As[k][ty*4]);
      float4 a1 = *(const float4*)(&As[k][64 + ty*4]);
      float4 b0 = *(const float4*)(&Bs[k][tx*4]);
      float4 b1 = *(const float4*)(&Bs[k][64 + tx*4]);
      float av[2][4] = {{a0.x,a0.y,a0.z,a0.w},{a1.x,a1.y,a1.z,a1.w}};
      float bv[2][4] = {{b0.x,b0.y,b0.z,b0.w},{b1.x,b1.y,b1.z,b1.w}};
      #pragma unroll
      for (int qa_ = 0; qa_ < 2; ++qa_)
        #pragma unroll
        for (int qb_ = 0; qb_ < 2; ++qb_)
          #pragma unroll
          for (int x = 0; x < 4; ++x)
            #pragma unroll
            for (int y = 0; y < 4; ++y)
              acc[qa_][qb_][x][y] += av[qa_][x]*bv[qb_][y];
    }
  }

  #pragma unroll
  for (int qa_ = 0; qa_ < 2; ++qa_)
    #pragma unroll
    for (int x = 0; x < 4; ++x) {
      int row = m0 + qa_*64 + ty*4 + x;
      if (row >= M) continue;
      #pragma unroll
      for (int qb_ = 0; qb_ < 2; ++qb_)
        #pragma unroll
        for (int y = 0; y < 4; ++y) {
          int col = n0 + qb_*64 + tx*4 + y;
          if (col < N) C[(size_t)row*N + col] = acc[qa_][qb_][x][y];
        }
    }
}

// ---------------- bf16 MFMA GEMM (guarded, for non-multiple shapes) ----------------
template<int OUTBF>
__global__ __launch_bounds__(256) void gemm_bf16k(const u16* __restrict__ A,
                                                  const u16* __restrict__ W,
                                                  void* __restrict__ C,
                                                  int M, int N, int K) {
  __shared__ __bf16 As[128][40];
  __shared__ __bf16 Bs[128][40];
  const int t = threadIdx.x;
  const int m0 = blockIdx.y << 7, n0 = blockIdx.x << 7;
  const int wave = t >> 6, lane = t & 63;
  const int wm = (wave >> 1) << 6, wn = (wave & 1) << 6;
  const int lr = lane & 15, ls = lane >> 4;
  f32x4 acc[4][4] = {};
  for (int k0 = 0; k0 < K; k0 += 32) {
    __syncthreads();
    #pragma unroll
    for (int s2 = 0; s2 < 2; ++s2) {
      int idx = t + (s2 << 8);
      int r = idx >> 2, c4 = (idx & 3) << 3;
      uint4 av = {0,0,0,0}, bv = {0,0,0,0};
      int gm = m0 + r, gn = n0 + r;
      if (gm < M) av = *(const uint4*)(A + (size_t)gm*K + k0 + c4);
      if (gn < N) bv = *(const uint4*)(W + (size_t)gn*K + k0 + c4);
      *(uint4*)(&As[r][c4]) = av;
      *(uint4*)(&Bs[r][c4]) = bv;
    }
    __syncthreads();
    bf16x8 af[4], bfr[4];
    #pragma unroll
    for (int x = 0; x < 4; ++x) af[x]  = *(const bf16x8*)(&As[wm + x*16 + lr][ls*8]);
    #pragma unroll
    for (int x = 0; x < 4; ++x) bfr[x] = *(const bf16x8*)(&Bs[wn + x*16 + lr][ls*8]);
    #pragma unroll
    for (int mi = 0; mi < 4; ++mi)
      #pragma unroll
      for (int ni = 0; ni < 4; ++ni)
        acc[mi][ni] = __builtin_amdgcn_mfma_f32_16x16x32_bf16(af[mi], bfr[ni], acc[mi][ni], 0, 0, 0);
  }
  #pragma unroll
  for (int mi = 0; mi < 4; ++mi)
    #pragma unroll
    for (int ni = 0; ni < 4; ++ni)
      #pragma unroll
      for (int r = 0; r < 4; ++r) {
        int row = m0 + wm + mi*16 + ls*4 + r;
        int col = n0 + wn + ni*16 + lr;
        if (row < M && col < N) {
          float v = acc[mi][ni][r];
          if (OUTBF) ((u16*)C)[(size_t)row*N + col] = f2bf(v);
          else       ((float*)C)[(size_t)row*N + col] = v;
        }
      }
}

// ---------------- fast bf16 MFMA GEMM (m97 structure): M,N mult of 128, K mult of 32 ----------------
template<int OUTBF>
__global__ __launch_bounds__(256) void gemm_bf16f(const u16* __restrict__ A,
                                                  const u16* __restrict__ W,
                                                  void* __restrict__ C,
                                                  int M, int N, int K) {
  __shared__ u16 As[128*32];
  __shared__ u16 Bs[128*32];
  const int t = threadIdx.x;
  const int m0 = blockIdx.y << 7, n0 = blockIdx.x << 7;
  const int wave = t >> 6, lane = t & 63;
  const int wm = (wave >> 1) << 6, wn = (wave & 1) << 6;
  const int lr = lane & 15, ls = lane >> 4;
  f32x4 acc[4][4] = {};
  for (int k0 = 0; k0 < K; k0 += 32) {
    __syncthreads();                       // readers of prev tile done
    #pragma unroll
    for (int s2 = 0; s2 < 2; ++s2) {
      int idx = t + (s2 << 8);
      int r = idx >> 2, c8 = (idx & 3) << 3;
      gload_lds16(A + (size_t)(m0+r)*K + k0 + c8, As + idx*8);
      gload_lds16(W + (size_t)(n0+r)*K + k0 + c8, Bs + idx*8);
    }
    __syncthreads();                       // drains vmcnt(0): LDS data visible
    bf16x8 af[4], bfr[4];
    #pragma unroll
    for (int x = 0; x < 4; ++x) af[x]  = *(const bf16x8*)(As + (wm + x*16 + lr)*32 + ls*8);
    #pragma unroll
    for (int x = 0; x < 4; ++x) bfr[x] = *(const bf16x8*)(Bs + (wn + x*16 + lr)*32 + ls*8);
    #pragma unroll
    for (int mi = 0; mi < 4; ++mi)
      #pragma unroll
      for (int ni = 0; ni < 4; ++ni)
        acc[mi][ni] = __builtin_amdgcn_mfma_f32_16x16x32_bf16(af[mi], bfr[ni], acc[mi][ni], 0, 0, 0);
  }
  #pragma unroll
  for (int mi = 0; mi < 4; ++mi)
    #pragma unroll
    for (int ni = 0; ni < 4; ++ni)
      #pragma unroll
      for (int r = 0; r < 4; ++r) {
        int row = m0 + wm + mi*16 + ls*4 + r;
        int col = n0 + wn + ni*16 + lr;
        float v = acc[mi][ni][r];
        if (OUTBF) ((u16*)C)[(size_t)row*N + col] = f2bf(v);
        else       ((float*)C)[(size_t)row*N + col] = v;
      }
}

// ---------------- RMSNorm (q path, 1536 cols, writes f32 in-place + bf16) ----------------
__global__ __launch_bounds__(256) void rms_q_kernel(float* __restrict__ qa,
                                                    const float* __restrict__ w,
                                                    u16* __restrict__ qres_b) {
  const int row = blockIdx.x, t = threadIdx.x;
  float* x = qa + (size_t)row*1536;
  float xs[6];
  float ss = 0.f;
  #pragma unroll
  for (int k = 0; k < 6; ++k) { xs[k] = x[t + k*256]; ss += xs[k]*xs[k]; }
  __shared__ float red[256];
  red[t] = ss; __syncthreads();
  for (int o = 128; o > 0; o >>= 1) { if (t < o) red[t] += red[t+o]; __syncthreads(); }
  float rms = rsqrtf(red[0]/1536.f + 1e-6f);
  #pragma unroll
  for (int k = 0; k < 6; ++k) {
    int c = t + k*256;
    float v = w[c] * (xs[k] * rms);
    x[c] = v;
    qres_b[(size_t)row*1536 + c] = f2bf(v);
  }
}

// ---------------- RMSNorm (kv path, first 512 of 576 cols -> bf16) ----------------
__global__ __launch_bounds__(256) void rms_kv_kernel(const float* __restrict__ ckv,
                                                     const float* __restrict__ w,
                                                     u16* __restrict__ kcomp) {
  const int row = blockIdx.x, t = threadIdx.x;
  const float* x = ckv + (size_t)row*576;
  float xs[2];
  float ss = 0.f;
  #pragma unroll
  for (int k = 0; k < 2; ++k) { xs[k] = x[t + k*256]; ss += xs[k]*xs[k]; }
  __shared__ float red[256];
  red[t] = ss; __syncthreads();
  for (int o = 128; o > 0; o >>= 1) { if (t < o) red[t] += red[t+o]; __syncthreads(); }
  float rms = rsqrtf(red[0]/512.f + 1e-6f);
  #pragma unroll
  for (int k = 0; k < 2; ++k) {
    int c = t + k*256;
    kcomp[(size_t)row*512 + c] = f2bf(w[c] * (xs[k] * rms));
  }
}

// ---------------- RoPE on q (in-place, bf16, dims 192..255) ----------------
__global__ __launch_bounds__(256) void rope_q_kernel(u16* __restrict__ q,
                                                     const float* __restrict__ cosb,
                                                     const float* __restrict__ sinb) {
  int gid = blockIdx.x*256 + threadIdx.x;      // 2048*32*32
  if (gid >= 2048*32*32) return;
  int i = gid >> 10, rem = gid & 1023;
  int h = rem >> 5, dd = rem & 31;
  size_t base = (size_t)i*8192 + h*256 + 192;
  float x1 = __uint_as_float(((u32)q[base+dd]) << 16);
  float x2 = __uint_as_float(((u32)q[base+dd+32]) << 16);
  float c1 = cosb[i*64+dd],   s1 = sinb[i*64+dd];
  float c2 = cosb[i*64+dd+32], s2 = sinb[i*64+dd+32];
  q[base+dd]    = f2bf(x1*c1 - x2*s1);
  q[base+dd+32] = f2bf(x2*c2 + x1*s2);
}

// ---------------- RoPE on k_pe (from ckv f32 cols 512..575 -> bf16 [2048,64]) ----------------
__global__ __launch_bounds__(256) void rope_k_kernel(const float* __restrict__ ckv,
                                                     const float* __restrict__ cosb,
                                                     const float* __restrict__ sinb,
                                                     u16* __restrict__ kpe) {
  int gid = blockIdx.x*256 + threadIdx.x;      // 2048*32
  if (gid >= 2048*32) return;
  int i = gid >> 5, dd = gid & 31;
  const float* xr = ckv + (size_t)i*576 + 512;
  float x1 = xr[dd], x2 = xr[dd+32];
  float c1 = cosb[i*64+dd],   s1 = sinb[i*64+dd];
  float c2 = cosb[i*64+dd+32], s2 = sinb[i*64+dd+32];
  kpe[(size_t)i*64+dd]    = f2bf(x1*c1 - x2*s1);
  kpe[(size_t)i*64+dd+32] = f2bf(x2*c2 + x1*s2);
}

// ---------------- transpose ikg [2048,68] -> ikT [64,2048] ----------------
__global__ __launch_bounds__(256) void transpose_ik(const float* __restrict__ ikg,
                                                    float* __restrict__ ikT) {
  int gid = blockIdx.x*256 + threadIdx.x;      // 64*2048
  if (gid >= 64*2048) return;
  int d = gid >> 11, j = gid & 2047;
  ikT[gid] = ikg[(size_t)j*68 + d];
}

// ---------------- indexer scores + exact top-512 (bitonic, jax tie-break) ----------------
__global__ __launch_bounds__(256) void topk_kernel(const float* __restrict__ iqv,
                                                   const float* __restrict__ ikT,
                                                   const float* __restrict__ ikg,
                                                   u32* __restrict__ maskbuf) {
  const int i = blockIdx.x, t = threadIdx.x;
  __shared__ float iqs[256];
  __shared__ float g[4];
  __shared__ u64 keys[2048];
  __shared__ u32 mk[64];
  iqs[t] = iqv[(size_t)i*256 + t];
  if (t < 4) g[t] = ikg[(size_t)i*68 + 64 + t];
  if (t < 64) mk[t] = 0;
  __syncthreads();
  float g0 = g[0], g1 = g[1], g2 = g[2], g3 = g[3];
  for (int j0 = 0; j0 < 2048; j0 += 256) {
    int j = j0 + t;
    float s;
    if (j > i) s = NEGF;
    else {
      float d0=0.f, d1=0.f, d2=0.f, d3=0.f;
      #pragma unroll 16
      for (int dd = 0; dd < 64; ++dd) {
        float v = ikT[dd*2048 + j];
        d0 += iqs[dd]*v; d1 += iqs[64+dd]*v; d2 += iqs[128+dd]*v; d3 += iqs[192+dd]*v;
      }
      s = g0*fmaxf(d0,0.f) + g1*fmaxf(d1,0.f) + g2*fmaxf(d2,0.f) + g3*fmaxf(d3,0.f);
    }
    keys[j] = ((u64)fkey(s) << 32) | (u32)(0xFFFFFFFFu - (u32)j);
  }
  __syncthreads();
  for (int k2 = 2; k2 <= 2048; k2 <<= 1) {
    for (int jj = k2 >> 1; jj > 0; jj >>= 1) {
      #pragma unroll 1
      for (int q8 = 0; q8 < 8; ++q8) {
        int x = t + (q8 << 8);
        int y = x ^ jj;
        if (y > x) {
          u64 kx = keys[x], ky = keys[y];
          if ((kx < ky) == ((x & k2) == 0)) { keys[x] = ky; keys[y] = kx; }
        }
      }
      __syncthreads();
    }
  }
  u32 ja = 0xFFFFFFFFu - (u32)(keys[t] & 0xFFFFFFFFull);
  u32 jb = 0xFFFFFFFFu - (u32)(keys[t+256] & 0xFFFFFFFFull);
  atomicOr(&mk[ja >> 5], 1u << (ja & 31));
  atomicOr(&mk[jb >> 5], 1u << (jb & 31));
  __syncthreads();
  if (t < 64) maskbuf[(size_t)i*64 + t] = mk[t];
}

// ---------------- MFMA flash attention pass1 ----------------
// DPP-based softmax butterfly (no LDS traffic for reduces); per-lane mask
// words loaded direct from global, prefetched one tile ahead.
__global__ __launch_bounds__(256, 3) void attn_pass1(
    const u16* __restrict__ qb, const u16* __restrict__ kvb,
    const u16* __restrict__ kpeb, const u32* __restrict__ maskbuf,
    float* __restrict__ probs, u16* __restrict__ attnb,
    float* __restrict__ Mb, float* __restrict__ Lb) {
  const int h = blockIdx.x & 31;
  const int qblk = 31 - (blockIdx.x >> 5);    // biggest-first
  const int i0 = qblk << 6;
  const int t = threadIdx.x;
  const int w = t >> 6;
  const int lane = t & 63;
  const int l15 = lane & 15, l4 = lane >> 4;
  const int i0w = i0 + (w << 4);

  __shared__ u16 Ks[32][264];       // keys x 256 dims, +8 pad (row 528B, 16-aligned)
  __shared__ u32 Vt2[16][260];      // key-pair x vdim (u32 = key-even | key-odd<<16), +4 pad
  __shared__ u16 Ps[4][16][40];     // per-wave P transform buffer

  const int c8 = t & 31;
  const int r0 = t >> 5;            // 0..7
  const u16* kbase = kvb + h*448;
  const u16* vbase = kvb + h*448 + 192;

  uint4 kreg[4];
  uint4 vreg0[2], vreg1[2];
  u32 mwn[4];

  auto prefetch = [&](int j0) {
    #pragma unroll
    for (int it = 0; it < 4; ++it) {
      int r = r0 + (it << 3);
      const u16* src = (c8 < 24)
        ? kbase + (size_t)(j0 + r)*14336 + c8*8
        : kpeb + (size_t)(j0 + r)*64 + (c8 - 24)*8;
      kreg[it] = *(const uint4*)src;
    }
    #pragma unroll
    for (int it = 0; it < 2; ++it) {
      int rp = r0 + (it << 3);
      const u16* vp = vbase + (size_t)(j0 + 2*rp)*14336 + c8*8;
      vreg0[it] = *(const uint4*)vp;
      vreg1[it] = *(const uint4*)(vp + 14336);
    }
  };
  auto prefetch_mask = [&](int jt) {
    #pragma unroll
    for (int r = 0; r < 4; ++r)
      mwn[r] = maskbuf[(size_t)(i0w + (l4<<2) + r)*64 + jt];
  };

  auto stage_store = [&]() {
    #pragma unroll
    for (int it = 0; it < 4; ++it)
      *(uint4*)(&Ks[r0 + (it << 3)][c8*8]) = kreg[it];
    #pragma unroll
    for (int it = 0; it < 2; ++it) {
      int rp = r0 + (it << 3);
      u32 a0 = vreg0[it].x, a1 = vreg0[it].y, a2 = vreg0[it].z, a3 = vreg0[it].w;
      u32 b0 = vreg1[it].x, b1 = vreg1[it].y, b2 = vreg1[it].z, b3 = vreg1[it].w;
      uint4 g0, g1;
      g0.x = (a0 & 0xffffu) | (b0 << 16);
      g0.y = (a0 >> 16)     | (b0 & 0xffff0000u);
      g0.z = (a1 & 0xffffu) | (b1 << 16);
      g0.w = (a1 >> 16)     | (b1 & 0xffff0000u);
      g1.x = (a2 & 0xffffu) | (b2 << 16);
      g1.y = (a2 >> 16)     | (b2 & 0xffff0000u);
      g1.z = (a3 & 0xffffu) | (b3 << 16);
      g1.w = (a3 >> 16)     | (b3 & 0xffff0000u);
      *(uint4*)(&Vt2[rp][c8*8])     = g0;
      *(uint4*)(&Vt2[rp][c8*8 + 4]) = g1;
    }
  };

  // Q fragments: A[m=l15][k=l4*8+e], 8 k-steps of 32
  bf16x8 qf[8];
  {
    const u16* qrow = qb + (size_t)(i0w + l15)*8192 + h*256 + l4*8;
    #pragma unroll
    for (int ks = 0; ks < 8; ++ks)
      qf[ks] = *(const bf16x8*)(qrow + ks*32);
  }
  f32x4 Of[16] = {};
  float mr[4] = {-INFINITY,-INFINITY,-INFINITY,-INFINITY};
  float lr[4] = {0.f,0.f,0.f,0.f};

  const int jt_end = (i0 + 63) >> 5;
  prefetch(0);
  prefetch_mask(0);
  for (int jt = 0; jt <= jt_end; ++jt) {
    const int j0 = jt << 5;
    __syncthreads();
    stage_store();                       // compiler inserts vmcnt waits for kreg/vreg
    u32 mword[4];
    #pragma unroll
    for (int r = 0; r < 4; ++r) mword[r] = mwn[r];
    if (jt < jt_end) { prefetch(j0 + 32); prefetch_mask(jt + 1); }
    __builtin_amdgcn_sched_barrier(0);
    asm volatile("s_waitcnt lgkmcnt(0)" ::: "memory");
    __builtin_amdgcn_s_barrier();
    __builtin_amdgcn_sched_barrier(0);   // rule #18: pin compute after the wait
    if (j0 > i0w + 15) continue;         // causal wave-level skip

    // S = Q K^T (2 key sub-tiles of 16)
    f32x4 sacc[2] = {};
    __builtin_amdgcn_s_setprio(1);
    #pragma unroll
    for (int nt = 0; nt < 2; ++nt)
      #pragma unroll
      for (int ks = 0; ks < 8; ++ks) {
        bf16x8 kf = *(const bf16x8*)(&Ks[nt*16 + l15][ks*32 + l4*8]);
        sacc[nt] = __builtin_amdgcn_mfma_f32_16x16x32_bf16(qf[ks], kf, sacc[nt], 0, 0, 0);
      }
    __builtin_amdgcn_s_setprio(0);

    float sv[2][4];
    #pragma unroll
    for (int nt = 0; nt < 2; ++nt)
      #pragma unroll
      for (int r = 0; r < 4; ++r) {
        int i_r = i0w + (l4<<2) + r;
        int j = j0 + nt*16 + l15;
        bool ok = (j <= i_r) && ((mword[r] >> (nt*16 + l15)) & 1u);
        sv[nt][r] = ok ? sacc[nt][r]*0.0625f : NEGF;
      }
    #pragma unroll
    for (int r = 0; r < 4; ++r) {
      int i_r = i0w + (l4<<2) + r;
      #pragma unroll
      for (int nt = 0; nt < 2; ++nt)
        if ((mword[r] >> (nt*16)) & 0xFFFFu)
          probs[((size_t)h*S + i_r)*S + j0 + nt*16 + l15] = sv[nt][r];
    }

    // online softmax: DPP butterfly over the 16-lane row group
    // {xor1, xor2, half_mirror(xor7), mirror(xor15)} spans the full group.
    float alpha[4];
    #pragma unroll
    for (int r = 0; r < 4; ++r) {
      float v = fmaxf(sv[0][r], sv[1][r]);
      v = fmaxf(v, DPPF(0xB1, v));    // quad_perm(1,0,3,2)
      v = fmaxf(v, DPPF(0x4E, v));    // quad_perm(2,3,0,1)
      v = fmaxf(v, DPPF(0x141, v));   // row_half_mirror
      v = fmaxf(v, DPPF(0x140, v));   // row_mirror
      float mn = fmaxf(mr[r], v);
      alpha[r] = (mn == mr[r]) ? 1.f : __expf(mr[r] - mn);
      mr[r] = mn;
    }
    float p0v[4], p1v[4];
    #pragma unroll
    for (int r = 0; r < 4; ++r) {
      float p0 = __expf(sv[0][r] - mr[r]);   // NEGF -> underflow 0
      float p1 = __expf(sv[1][r] - mr[r]);
      p0v[r] = p0; p1v[r] = p1;
      float rs = p0 + p1;
      rs += DPPF(0xB1, rs);
      rs += DPPF(0x4E, rs);
      rs += DPPF(0x141, rs);
      rs += DPPF(0x140, rs);
      lr[r] = lr[r]*alpha[r] + rs;
    }

    // P -> LDS (C-layout write), read back as A-frag
    #pragma unroll
    for (int r = 0; r < 4; ++r) {
      Ps[w][(l4<<2)+r][l15]      = f2bf(p0v[r]);
      Ps[w][(l4<<2)+r][16 + l15] = f2bf(p1v[r]);
    }
    bf16x8 pf = *(const bf16x8*)(&Ps[w][l15][l4*8]);

    // rescale O, then PV (V fragments from transposed Vt2, conflict-free b32 reads)
    #pragma unroll
    for (int vt = 0; vt < 16; ++vt)
      #pragma unroll
      for (int r = 0; r < 4; ++r)
        Of[vt][r] *= alpha[r];
    __builtin_amdgcn_s_setprio(1);
    #pragma unroll
    for (int vt = 0; vt < 16; ++vt) {
      uint4 uu;
      uu.x = Vt2[4*l4 + 0][vt*16 + l15];
      uu.y = Vt2[4*l4 + 1][vt*16 + l15];
      uu.z = Vt2[4*l4 + 2][vt*16 + l15];
      uu.w = Vt2[4*l4 + 3][vt*16 + l15];
      bf16x8 vf = *reinterpret_cast<const bf16x8*>(&uu);
      Of[vt] = __builtin_amdgcn_mfma_f32_16x16x32_bf16(pf, vf, Of[vt], 0, 0, 0);
    }
    __builtin_amdgcn_s_setprio(0);
  }

  // epilogue
  float invl[4];
  #pragma unroll
  for (int r = 0; r < 4; ++r) invl[r] = 1.f / lr[r];
  #pragma unroll
  for (int vt = 0; vt < 16; ++vt)
    #pragma unroll
    for (int r = 0; r < 4; ++r) {
      int i_r = i0w + (l4<<2) + r;
      attnb[(size_t)i_r*8192 + h*256 + vt*16 + l15] = f2bf(Of[vt][r]*invl[r]);
    }
  if (l15 == 0) {
    #pragma unroll
    for (int r = 0; r < 4; ++r) {
      Mb[(size_t)h*S + i0w + (l4<<2) + r] = mr[r];
      Lb[(size_t)h*S + i0w + (l4<<2) + r] = lr[r];
    }
  }
}

// ---------------- pass2: mask-aware softmax normalize of probs ----------------
__global__ __launch_bounds__(256) void attn_pass2(float* __restrict__ probs,
                                                  const float* __restrict__ Mb,
                                                  const float* __restrict__ Lb,
                                                  const u32* __restrict__ maskbuf) {
  const int i = blockIdx.x, h = blockIdx.y, t = threadIdx.x;
  const int j0 = t << 3;
  float* row = probs + ((size_t)h*S + i)*S;
  u32 bits = (maskbuf[(size_t)i*64 + (j0 >> 5)] >> (j0 & 31)) & 0xFFu;
  float4 o0 = {0.f,0.f,0.f,0.f}, o1 = {0.f,0.f,0.f,0.f};
  if (bits != 0 && j0 <= i) {
    const float m = Mb[(size_t)h*S + i];
    const float invl = 1.f / Lb[(size_t)h*S + i];
    float4 v0 = *(const float4*)(row + j0);
    float4 v1 = *(const float4*)(row + j0 + 4);
    o0.x = (((bits>>0)&1u) && j0+0 <= i) ? __expf(v0.x - m)*invl : 0.f;
    o0.y = (((bits>>1)&1u) && j0+1 <= i) ? __expf(v0.y - m)*invl : 0.f;
    o0.z = (((bits>>2)&1u) && j0+2 <= i) ? __expf(v0.z - m)*invl : 0.f;
    o0.w = (((bits>>3)&1u) && j0+3 <= i) ? __expf(v0.w - m)*invl : 0.f;
    o1.x = (((bits>>4)&1u) && j0+4 <= i) ? __expf(v1.x - m)*invl : 0.f;
    o1.y = (((bits>>5)&1u) && j0+5 <= i) ? __expf(v1.y - m)*invl : 0.f;
    o1.z = (((bits>>6)&1u) && j0+6 <= i) ? __expf(v1.z - m)*invl : 0.f;
    o1.w = (((bits>>7)&1u) && j0+7 <= i) ? __expf(v1.w - m)*invl : 0.f;
  }
  *(float4*)(row + j0) = o0;
  *(float4*)(row + j0 + 4) = o1;
}

// ---------------- host launch ----------------
extern "C" void kernel_launch(void* const* d_in, const int* in_sizes, int n_in,
                              void* d_out, int out_size, void* d_ws, size_t ws_size,
                              hipStream_t stream) {
  (void)in_sizes; (void)n_in; (void)out_size;
  const float* hidden    = (const float*)d_in[0];
  const float* cosb      = (const float*)d_in[1];
  const float* sinb      = (const float*)d_in[2];
  const float* q_a_w     = (const float*)d_in[3];
  const float* q_a_ln    = (const float*)d_in[4];
  const float* q_b_w     = (const float*)d_in[5];
  const float* kv_a_w    = (const float*)d_in[6];
  const float* kv_a_ln   = (const float*)d_in[7];
  const float* kv_b_w    = (const float*)d_in[8];
  const float* o_w       = (const float*)d_in[9];
  const float* idx_q_w   = (const float*)d_in[10];
  const float* idx_k_w   = (const float*)d_in[11];
  const float* idx_gate_w= (const float*)d_in[12];
  float* out   = (float*)d_out;
  float* probs = out + (size_t)2048*4096;

  char* wp = (char*)d_ws;
  auto alloc = [&](size_t bytes) { char* p = wp; wp += (bytes + 255) & ~(size_t)255; return p; };
  float* qa      = (float*)alloc((size_t)2048*1536*4);
  float* iq      = (float*)alloc((size_t)2048*256*4);
  float* ikg     = (float*)alloc((size_t)68*4096*4);
  float* ikgo    = (float*)alloc((size_t)2048*68*4);
  float* ikT     = (float*)alloc((size_t)64*2048*4);
  float* ckv     = (float*)alloc((size_t)2048*576*4);
  u16* hidden_b  = (u16*)alloc((size_t)2048*4096*2);
  u16* qres_b    = (u16*)alloc((size_t)2048*1536*2);
  u16* qbw_b     = (u16*)alloc((size_t)8192*1536*2);
  u16* kvaw_b    = (u16*)alloc((size_t)576*4096*2);
  u16* kvbw_b    = (u16*)alloc((size_t)14336*512*2);
  u16* ow_b      = (u16*)alloc((size_t)4096*8192*2);
  u16* qB        = (u16*)alloc((size_t)2048*8192*2);
  u16* kcomp_b   = (u16*)alloc((size_t)2048*512*2);
  u16* kpe_b     = (u16*)alloc((size_t)2048*64*2);
  u16* kvB       = (u16*)alloc((size_t)2048*14336*2);
  u16* attn_b    = (u16*)alloc((size_t)2048*8192*2);
  u32* maskb     = (u32*)alloc((size_t)2048*64*4);
  float* Mb      = (float*)alloc((size_t)32*2048*4);
  float* Lb      = (float*)alloc((size_t)32*2048*4);

  // split-K partial buffers (guarded by ws_size; fallback keeps old path)
  size_t used = (size_t)(wp - (char*)d_ws);
  size_t need = ((size_t)4*2048*1536*4 + 256) + ((size_t)4*2048*256*4 + 256)
              + ((size_t)8*2048*68*4 + 256);
  bool split = (used + need <= ws_size);
  float *paq = nullptr, *pai = nullptr, *pag = nullptr;
  if (split) {
    paq = (float*)alloc((size_t)4*2048*1536*4);
    pai = (float*)alloc((size_t)4*2048*256*4);
    pag = (float*)alloc((size_t)8*2048*68*4);
  }

  dim3 blk(256);
  // bf16 copies
  cvt_bf16<<<8192,  blk, 0, stream>>>(hidden, (u32*)hidden_b, 2097152);
  cvt_bf16<<<12288, blk, 0, stream>>>(q_b_w,  (u32*)qbw_b,   3145728);
  cvt_bf16<<<2304,  blk, 0, stream>>>(kv_a_w, (u32*)kvaw_b,   589824);
  cvt_bf16<<<7168,  blk, 0, stream>>>(kv_b_w, (u32*)kvbw_b,  1835008);
  cvt_bf16<<<32768, blk, 0, stream>>>(o_w,    (u32*)ow_b,    8388608);
  concat_ikg<<<272, blk, 0, stream>>>(idx_k_w, idx_gate_w, ikg);
  // fp32 precision path (indexer) — split-K for occupancy
  if (split) {
    gemm_f32_v3<<<dim3(12,16,4), blk, 0, stream>>>(hidden, q_a_w, paq, 2048, 1536, 4096, 1024);
    reduce_part<<<3072, blk, 0, stream>>>(paq, qa, 786432, 4);
    gemm_f32_v3<<<dim3(1,16,8),  blk, 0, stream>>>(hidden, ikg,   pag, 2048, 68,   4096, 512);
    reduce_part<<<136,  blk, 0, stream>>>(pag, ikgo, 34816, 8);
    rms_q_kernel<<<2048, blk, 0, stream>>>(qa, q_a_ln, qres_b);
    gemm_f32_v3<<<dim3(2,16,4),  blk, 0, stream>>>(qa, idx_q_w, pai, 2048, 256, 1536, 384);
    reduce_part<<<512,  blk, 0, stream>>>(pai, iq, 131072, 4);
  } else {
    gemm_f32_v2<<<dim3(12,16), blk, 0, stream>>>(hidden, q_a_w, qa,   2048, 1536, 4096);
    gemm_f32_v2<<<dim3(1,16),  blk, 0, stream>>>(hidden, ikg,   ikgo, 2048, 68,   4096);
    rms_q_kernel<<<2048, blk, 0, stream>>>(qa, q_a_ln, qres_b);
    gemm_f32_v2<<<dim3(2,16),  blk, 0, stream>>>(qa, idx_q_w, iq, 2048, 256, 1536);
  }
  transpose_ik<<<512, blk, 0, stream>>>(ikgo, ikT);
  // bf16 path
  gemm_bf16k<0><<<dim3(5,16),   blk, 0, stream>>>(hidden_b, kvaw_b, ckv, 2048, 576,   4096);
  rms_kv_kernel<<<2048, blk, 0, stream>>>(ckv, kv_a_ln, kcomp_b);
  rope_k_kernel<<<256, blk, 0, stream>>>(ckv, cosb, sinb, kpe_b);
  gemm_bf16f<1><<<dim3(64,16),  blk, 0, stream>>>(qres_b, qbw_b, qB, 2048, 8192, 1536);
  rope_q_kernel<<<8192, blk, 0, stream>>>(qB, cosb, sinb);
  gemm_bf16f<1><<<dim3(112,16), blk, 0, stream>>>(kcomp_b, kvbw_b, kvB, 2048, 14336, 512);
  // top-k + attention
  topk_kernel<<<2048, blk, 0, stream>>>(iq, ikT, ikgo, maskb);
  attn_pass1<<<dim3(1024), blk, 0, stream>>>(qB, kvB, kpe_b, maskb, probs, attn_b, Mb, Lb);
  attn_pass2<<<dim3(2048,32), blk, 0, stream>>>(probs, Mb, Lb, maskb);
  // output projection
  gemm_bf16f<0><<<dim3(32,16), blk, 0, stream>>>(attn_b, ow_b, out, 2048, 4096, 8192);
}